// Round 17
// baseline (523.031 us; speedup 1.0000x reference)
//
#include <hip/hip_runtime.h>
#include <hip/hip_bf16.h>
#include <stdint.h>

#define SEQ    16384
#define NKL    11
#define NSTEP  467
#define GSTEPS 8
#define NGRP   ((NSTEP + GSTEPS - 1)/GSTEPS)   // 59
#define PAD    128
#define SNLO   1152
#define SNHI   17544
#define SROWS  (SNLO + SNHI)   // 18696
#define P1T    261
#define G2T    1104

typedef __attribute__((ext_vector_type(8))) short short8;
typedef __attribute__((ext_vector_type(4))) float f32x4;

__host__ __device__ inline int arrUlo(int a){
  if (a == 0) return 0;
  if (a <= 9) return -(2*(1<<a) - 1);
  int lv = (a <= 18) ? (a-9) : (a-18);
  return -((1<<lv) - 1);
}
__host__ __device__ inline int arrRowsP(int a){ return SEQ - arrUlo(a) + 2*PAD; }
__host__ __device__ inline long arrOff(int a){ long o=0; for (int k=0;k<a;k++) o += arrRowsP(k); return o; }
__host__ __device__ inline long totRows(){ return arrOff(28); }

__device__ inline float multf(int l){ return (float)(pow(0.5, (double)l/4096.0)*0.9 + 0.1); }
__device__ inline float Kv(const float* kern, int l, int g, int o, int i, int p){
  return kern[ (((size_t)((l*2 + g)*32 + o))*32 + i)*16 + p ];
}
__device__ inline ushort bfb(float v){
  return __builtin_bit_cast(ushort, __float2bfloat16(v));
}

struct Step { int arr; int c; int l; int g; int kidx; float coeff; };

__device__ inline Step decode(int st){
  Step r;
  if (st == 0){ r = {0, 0, 0, 0, 0, 1.f}; return r; }
  if (st < 17){ int p = st-1;  r = {0, 1+p,  0, 1, p, 1.f}; return r; }
  if (st < 33){ int p = st-17; r = {0, -1-p, 0, 0, p, 1.f}; return r; }
  if (st < 465){
    int t = st-33; int blk = t/24, k = t%24;
    int l = 1 + blk/2; int g = (blk & 1) ? 0 : 1;
    int s = 1<<l, hs = s>>1, off = 16*(s-1);
    float inv2s = 0.5f/(float)s;
    int arrT = l, arrB1 = 9+l, arrM = 18+l, arrH = (l==1) ? 0 : (8+l);
    if (k < 18){
      int p = k-1; int pp = p < 0 ? 0 : (p > 15 ? 15 : p);
      int c = g ? (1+off+p*s-hs) : (-off-p*s-3*hs);
      r = {arrT, c, l, g, pp, inv2s}; return r;
    }
    int kk = k-18;
    if (g){
      int c3 = 1+off-3*hs, c3h = 1+off-hs, c4 = 1+off+16*s+hs, c4h = 1+off+16*s;
      switch(kk){
        case 0: r = {arrM,  c3,  l, g, 0,  -2.f*inv2s}; return r;
        case 1: r = {arrB1, c3,  l, g, 0,  -inv2s}; return r;
        case 2: r = {arrH,  c3h, l, g, 0,  -1.f}; return r;
        case 3: r = {arrB1, c4,  l, g, 15, -(2.f*s-1.f)*inv2s}; return r;
        case 4: r = {arrM,  c4,  l, g, 15, +2.f*inv2s}; return r;
        default:r = {arrH,  c4h, l, g, 15, -1.f}; return r;
      }
    } else {
      int c3 = -off+hs, c3h = -off, c4 = -off-17*s-hs, c4h = -off-16*s-hs;
      switch(kk){
        case 0: r = {arrB1, c3,  l, g, 0,  -(2.f*s-1.f)*inv2s}; return r;
        case 1: r = {arrM,  c3,  l, g, 0,  +2.f*inv2s}; return r;
        case 2: r = {arrH,  c3h, l, g, 0,  -1.f}; return r;
        case 3: r = {arrM,  c4,  l, g, 15, -2.f*inv2s}; return r;
        case 4: r = {arrB1, c4,  l, g, 15, -inv2s}; return r;
        default:r = {arrH,  c4h, l, g, 15, -1.f}; return r;
      }
    }
  }
  if (st == 465){ r = {13, 16369, 10, 1, 0, 1.f}; return r; }
  r = {13, -16384, 10, 0, 0, 1.f}; return r;
}

// ================= device bodies =================

__device__ void normBody(const float* __restrict__ kern, const float* __restrict__ cen,
                         float* __restrict__ invn, int bid, int tid, char* shm){
  double* sred = (double*)shm;
  int o = bid >> 5, i = bid & 31;
  float mlt[NKL];
  for (int l = 0; l < NKL; l++) mlt[l] = multf(l);
  double acc = 0.0;
  for (int pos = tid; pos < 2*SEQ; pos += 256){
    int r = pos & (SEQ-1);
    int lr = (r >> 4) + 1;
    int l  = 31 - __clz(lr);
    int s  = 1 << l;
    int j  = r - 16*(s - 1);
    float c = (j + 0.5f)/(float)s - 0.5f;
    c = fminf(fmaxf(c, 0.f), 15.f);
    int i0 = (int)floorf(c);
    int i1 = (i0+1 < 15) ? i0+1 : 15;
    float w = c - (float)i0;
    int g = pos >> 14;
    float v = Kv(kern,l,g,o,i,i0)*(1.f-w) + Kv(kern,l,g,o,i,i1)*w;
    v *= mlt[l];
    acc += (double)v * v;
  }
  sred[tid] = acc; __syncthreads();
  for (int ofs = 128; ofs > 0; ofs >>= 1){ if (tid < ofs) sred[tid] += sred[tid+ofs]; __syncthreads(); }
  if (tid == 0){
    float cc = cen[o*32 + i];
    double tot = sred[0] + (double)cc*cc;
    invn[o*32 + i] = (float)(1.0 / sqrt(tot));
  }
}

__device__ void setupBody(int4* __restrict__ stab, int bid, int tid){
  int st = bid*256 + tid;
  if (st >= NSTEP) return;
  Step sp = decode(st);
  int ulo = arrUlo(sp.arr);
  long base = arrOff(sp.arr) + (sp.c - ulo) + PAD;
  int y = ulo - 255 - sp.c;
  stab[st] = make_int4((int)base, y, SEQ - 1 - sp.c, (int)(base + y + 127));
}

__device__ void wtsBody(const float* __restrict__ kern, const float* __restrict__ cen,
                        const float* __restrict__ invn, __hip_bfloat16* __restrict__ wts,
                        int st, int tid){
  Step sp = decode(st);
  float m = multf(sp.l);
  for (int idx = tid; idx < 1024; idx += 256){
    int o = idx >> 5, i = idx & 31;
    float in = invn[o*32 + i];
    float w;
    if (st == 0) w = cen[o*32 + i] * in;
    else         w = m * Kv(kern, sp.l, sp.g, o, i, sp.kidx) * in * sp.coeff;
    int sidx = idx ^ (((o >> 1) & 3) << 3);
    wts[(size_t)st*1024 + sidx] = __float2bfloat16(w);
  }
}

__device__ void pfsBody(const float* __restrict__ x, double* __restrict__ tmp,
                        double* __restrict__ tmpT, int bid, int tid, char* shm){
  double* sc1 = (double*)shm;
  double* sc2 = sc1 + 256;
  double* scr = sc2 + 256;
  double* tots = scr + 256;
  int b = bid >> 5, i = bid & 31;
  const float* xp = x + (((size_t)(b*32 + i)) << 14);
  int n0 = tid * 64;
  double lp = 0.0, lsum = 0.0, rsum = 0.0;
  for (int e = 0; e < 64; e++){
    double xv = (double)xp[n0 + e];
    lsum += lp;
    lp += xv;
    rsum += (double)(n0 + e) * xv;
  }
  sc1[tid] = lp; sc2[tid] = lsum; scr[tid] = rsum;
  __syncthreads();
  if (tid == 0){
    double a1 = 0, a2 = 0, ar = 0;
    for (int t = 0; t < 256; t++){
      double l1 = sc1[t], l2 = sc2[t], lr = scr[t];
      sc1[t] = a1; sc2[t] = a2; scr[t] = ar;
      a2 += 64.0*a1 + l2;
      a1 += l1;
      ar += lr;
    }
    tots[0] = a1; tots[1] = a2; tots[2] = ar;
  }
  __syncthreads();
  double s1v = sc1[tid], s2v = sc2[tid], r1v = scr[tid];
  double* tp = tmp + ((size_t)((b*32 + i)*256 + tid)) * 12;
  for (int e = 0; e < 64; e++){
    if ((e & 15) == 0){
      int q = e >> 4;
      tp[q*3+0] = s1v; tp[q*3+1] = s2v; tp[q*3+2] = r1v;
    }
    double xv = (double)xp[n0 + e];
    s2v += s1v; s1v += xv; r1v += (double)(n0 + e) * xv;
  }
  if (tid == 0){
    double* tt = tmpT + (size_t)(b*32 + i)*3;
    tt[0] = tots[0]; tt[1] = tots[1]; tt[2] = tots[2];
  }
}

__device__ void pfeBody(const float* __restrict__ x, const double* __restrict__ tmp,
                        const double* __restrict__ tmpT,
                        float* __restrict__ S1c, float* __restrict__ S2c, float* __restrict__ R1c,
                        int gb, int tid, int b0){
  int blocal = gb >> 7, bx = gb & 127;
  int i = tid & 31, sj = tid >> 5;
  int sub = bx*8 + sj;
  int b = b0 + blocal;
  const double* tp = tmp + ((size_t)((b*32 + i)*1024 + sub)) * 3;
  double s1v = tp[0], s2v = tp[1], r1v = tp[2];
  const float* xp = x + (((size_t)(b*32 + i)) << 14);
  float* o1 = S1c + (size_t)blocal * SROWS * 32 + i;
  float* o2 = S2c + (size_t)blocal * SROWS * 32 + i;
  float* o3 = R1c + (size_t)blocal * SROWS * 32 + i;
  int n0 = sub * 16;
  for (int e = 0; e < 16; e++){
    int n = n0 + e;
    size_t row = (size_t)(n + SNLO) * 32;
    o1[row] = (float)s1v; o2[row] = (float)s2v; o3[row] = (float)r1v;
    double xv = (double)xp[n];
    s2v += s1v; s1v += xv; r1v += (double)n * xv;
  }
  float* p1b = S1c + (size_t)blocal * SROWS * 32;
  float* p2b = S2c + (size_t)blocal * SROWS * 32;
  float* p3b = R1c + (size_t)blocal * SROWS * 32;
  int flat = bx*256 + tid;
  for (int idx = flat; idx < SNLO*32; idx += 32768){
    p1b[idx] = 0.f; p2b[idx] = 0.f; p3b[idx] = 0.f;
  }
  const double* tt = tmpT + (size_t)b*32*3;
  for (int idx = flat; idx < (SNHI-SEQ)*32; idx += 32768){
    int r = idx >> 5, ii = idx & 31;
    double T1 = tt[ii*3], T2 = tt[ii*3+1], TR = tt[ii*3+2];
    size_t ofs = (size_t)(SEQ + SNLO) * 32 + idx;
    p1b[ofs] = (float)T1;
    p2b[ofs] = (float)(T2 + (double)r * T1);
    p3b[ofs] = (float)TR;
  }
}

__device__ void p1Body(const float* __restrict__ x, __hip_bfloat16* __restrict__ tr,
                       int bid, int tid, char* shm, int b0, long tR){
  float* Xb = (float*)shm;
  float* Ab = Xb + 4096;
  float* Bb = Ab + 4096;
  float* Db = Bb + 4096;
  int bl = bid / P1T, bx = bid % P1T;
  int b = b0 + bl;
  int S0 = -192 + bx*64;
  ushort* trb = (ushort*)tr + (size_t)bl * tR * 32;

  {
    int i = tid >> 3, seg = tid & 7;
    const float* xp = x + (((size_t)(b*32 + i)) << 14);
    for (int e = 0; e < 16; e++){
      int ul = seg*16 + e; int u = S0 + ul;
      Xb[ul*32 + i] = (u >= 0 && u < SEQ) ? xp[u] : 0.f;
    }
  }
  __syncthreads();

  auto storeArr = [&](const float* src, int arr){
    int ulo = arrUlo(arr); long ofs = arrOff(arr);
    unsigned rows = (unsigned)(SEQ - ulo + 2*PAD);
    for (int e2 = 0; e2 < 4; e2++){
      int f2 = e2*256 + tid;
      int ul = f2 >> 4, j = (f2 & 15)*2;
      unsigned p = (unsigned)(S0 + ul - (ulo - PAD));
      if (p < rows){
        ushort2 pk;
        pk.x = bfb(src[ul*32 + j]);
        pk.y = bfb(src[ul*32 + j + 1]);
        *(ushort2*)(trb + ((size_t)(ofs + p))*32 + j) = pk;
      }
    }
  };
  auto storeT = [&](const float* nx, int arr){
    int ulo = arrUlo(arr); long ofs = arrOff(arr);
    unsigned rows = (unsigned)(SEQ - ulo + 2*PAD);
    for (int e2 = 0; e2 < 4; e2++){
      int f2 = e2*256 + tid;
      int ul = f2 >> 4, j = (f2 & 15)*2;
      unsigned p = (unsigned)(S0 + ul - (ulo - PAD));
      if (p < rows){
        ushort2 pk;
        pk.x = bfb(nx[ul*32 + j]     + nx[(ul+1)*32 + j]);
        pk.y = bfb(nx[ul*32 + j + 1] + nx[(ul+1)*32 + j + 1]);
        *(ushort2*)(trb + ((size_t)(ofs + p))*32 + j) = pk;
      }
    }
  };

  {
    const float* cur = Xb; float* nxt = Ab;
    #pragma unroll
    for (int l = 1; l <= 5; l++){
      int sp32 = (1 << (l-1)) * 32;
      int LIM = 130 - (2 << l);
      for (int e2 = 0; e2 < 16; e2++){
        int flat = e2*256 + tid;
        if ((flat >> 5) < LIM)
          nxt[flat] = cur[flat] + 2.f*cur[flat + sp32] + cur[flat + 2*sp32];
      }
      __syncthreads();
      storeT(nxt, l);
      cur = nxt; nxt = (l & 1) ? Bb : Ab;
    }
  }
  __syncthreads();
  {
    for (int e2 = 0; e2 < 16; e2++){
      int flat = e2*256 + tid;
      if ((flat >> 5) < 127){
        Ab[flat] = Xb[flat] + Xb[flat + 32];
        Db[flat] = Xb[flat + 32];
      }
    }
    __syncthreads();
    storeArr(Ab, 10); storeArr(Db, 19);
    float* bc = Ab; float* mc = Db; float* bn = Xb; float* mn = Bb;
    #pragma unroll
    for (int l = 2; l <= 5; l++){
      int sp = 1 << (l-1), sp32 = sp*32;
      int LIM = 129 - (1 << l);
      float fs = (float)sp;
      for (int e2 = 0; e2 < 16; e2++){
        int flat = e2*256 + tid;
        if ((flat >> 5) < LIM){
          float bwv = bc[flat + sp32];
          bn[flat] = bc[flat] + bwv;
          mn[flat] = mc[flat] + mc[flat + sp32] + fs*bwv;
        }
      }
      __syncthreads();
      storeArr(bn, 9 + l); storeArr(mn, 18 + l);
      float* t1 = bc; bc = bn; bn = t1;
      float* t2 = mc; mc = mn; mn = t2;
    }
  }
}

__device__ void gen2Body(const float* __restrict__ S1p, const float* __restrict__ S2p,
                         const float* __restrict__ R1p, __hip_bfloat16* __restrict__ tr,
                         int gb0, int nG, int tid, int s0, long tR){
  int gb = (gb0 & 7) * (nG >> 3) + (gb0 >> 3);
  int bl = gb / G2T, bx = gb - bl*G2T;
  int i = tid & 31, ug = tid >> 5;
  ushort* trb = (ushort*)tr + (size_t)(s0 + bl) * tR * 32;
  const float* s1 = S1p + (size_t)bl * SROWS * 32 + i;
  const float* s2 = S2p + (size_t)bl * SROWS * 32 + i;
  const float* r1 = R1p + (size_t)bl * SROWS * 32 + i;
  for (int e = 0; e < 2; e++){
    int u = -SNLO + bx*16 + e*8 + ug;
    size_t ns = (size_t)(u + SNLO) * 32;
    float s1_0 = s1[ns], s1_1 = s1[ns + 32];
    float s2_0 = s2[ns], s2_1 = s2[ns + 32];
    float r1_0 = r1[ns];
    {
      unsigned p = (unsigned)(u + PAD);
      if (p < (unsigned)(SEQ + 2*PAD))
        trb[((size_t)(arrOff(0) + p))*32 + i] = bfb(s1_1 - s1_0);
    }
    #pragma unroll
    for (int li = 0; li < 4; li++){
      const int l = 6 + li;
      const int s = 1 << l;
      float sa = s2[ns + (size_t)s*32],      sb = s2[ns + (size_t)(s+1)*32];
      float sc2 = s2[ns + (size_t)(2*s)*32], sd = s2[ns + (size_t)(2*s+1)*32];
      float Tv = (sc2 + sd) - 2.f*(sa + sb) + (s2_0 + s2_1);
      float b1v = s1[ns + (size_t)s*32] - s1_0;
      float mv  = (r1[ns + (size_t)s*32] - r1_0) - (float)u * b1v;
      {
        int ulo = -(2*s - 1);
        unsigned p = (unsigned)(u - (ulo - PAD));
        if (p < (unsigned)(SEQ - ulo + 2*PAD))
          trb[((size_t)(arrOff(l) + p))*32 + i] = bfb(Tv);
      }
      {
        int ulo = -(s - 1);
        unsigned p = (unsigned)(u - (ulo - PAD));
        unsigned rows = (unsigned)(SEQ - ulo + 2*PAD);
        if (p < rows){
          trb[((size_t)(arrOff(9 + l) + p))*32 + i]  = bfb(b1v);
          trb[((size_t)(arrOff(18 + l) + p))*32 + i] = bfb(mv);
        }
      }
    }
  }
}

// ================= fused kernels =================

__global__ __launch_bounds__(256) void fuseA_k(const float* __restrict__ x,
                                               const float* __restrict__ kern,
                                               const float* __restrict__ cen,
                                               float* __restrict__ invn,
                                               int4* __restrict__ stab,
                                               double* __restrict__ tmp,
                                               double* __restrict__ tmpT,
                                               __hip_bfloat16* __restrict__ tr,
                                               int nP1, int nNorm, int nPfs, int b0, long tR){
  __shared__ __align__(16) char shm[65536];
  int bid = blockIdx.x, tid = threadIdx.x;
  if (bid < nP1){ p1Body(x, tr, bid, tid, shm, b0, tR); return; }
  bid -= nP1;
  if (bid < nNorm){ normBody(kern, cen, invn, bid, tid, shm); return; }
  bid -= nNorm;
  if (nNorm > 0 && bid < 2){ setupBody(stab, bid, tid); return; }
  if (nNorm > 0) bid -= 2;
  if (bid < nPfs) pfsBody(x, tmp, tmpT, bid, tid, shm);
}

__global__ __launch_bounds__(256) void fuseB_k(const float* __restrict__ kern,
                                               const float* __restrict__ cen,
                                               const float* __restrict__ invn,
                                               __hip_bfloat16* __restrict__ wts,
                                               const float* __restrict__ x,
                                               const double* __restrict__ tmp,
                                               const double* __restrict__ tmpT,
                                               float* __restrict__ S1c, float* __restrict__ S2c,
                                               float* __restrict__ R1c,
                                               int nWts, int nPfe, int b0){
  int bid = blockIdx.x, tid = threadIdx.x;
  if (bid < nWts){ wtsBody(kern, cen, invn, wts, bid, tid); return; }
  bid -= nWts;
  if (bid < nPfe) pfeBody(x, tmp, tmpT, S1c, S2c, R1c, bid, tid, b0);
}

__global__ __launch_bounds__(256) void fuseC_k(const float* __restrict__ S1a,
                                               const float* __restrict__ S2a,
                                               const float* __restrict__ R1a,
                                               __hip_bfloat16* __restrict__ tr,
                                               int nGen2, int s0g, long tR,
                                               const float* __restrict__ x,
                                               const double* __restrict__ tmp,
                                               const double* __restrict__ tmpT,
                                               float* __restrict__ S1b, float* __restrict__ S2b,
                                               float* __restrict__ R1b,
                                               int nPfe, int b0p){
  int bid = blockIdx.x, tid = threadIdx.x;
  if (bid < nGen2){ gen2Body(S1a, S2a, R1a, tr, bid, nGen2, tid, s0g, tR); return; }
  bid -= nGen2;
  if (bid < nPfe) pfeBody(x, tmp, tmpT, S1b, S2b, R1b, bid, tid, b0p);
}

// ================= GEMM: r13 pipeline, LDS-padded to force 1 block/CU =================
__device__ inline void gload16(const void* g, void* l){
  __builtin_amdgcn_global_load_lds(
      (const __attribute__((address_space(1))) void*)g,
      (__attribute__((address_space(3))) void*)l, 16, 0, 0);
}

__global__ __launch_bounds__(256) void gemm11_k(const short* __restrict__ tr,
                                                const short* __restrict__ wts,
                                                const int4* __restrict__ stab,
                                                float* __restrict__ out,
                                                int b0, long tR){
  __shared__ int4 sstab[NSTEP];
  // 76 KB: with sstab (7.3 KB) total >80 KB -> exactly 1 block/CU resident.
  // L1 (32 KB) then holds prev 16 KB A-panel + incoming panel -> cross-step
  // window overlap (tent taps shift by s=2..128 rows) becomes L1 hits.
  __shared__ __align__(16) char smem[77824];
  short* Wlds = (short*)smem;
  int tid = threadIdx.x, wid = tid >> 6, lane = tid & 63;
  int N = gridDim.x;
  int wg = (blockIdx.x & 7) * (N >> 3) + (blockIdx.x >> 3);
  int bl = wg >> 6, T0 = (wg & 63) << 8;
  int b = b0 + bl;
  int rowlane = lane & 15, chunk = lane >> 4;
  const short* trb = tr + (size_t)bl * tR * 32;
  const char* wbase = (const char*)wts;
  int rowbase = wid*64 + rowlane;
  int chunkoff = chunk*8;
  int voffA = rowbase*32 + chunkoff;
  int offw = (rowlane*32 + chunk*8) ^ (((rowlane >> 1) & 3) << 3);
  f32x4 acc00={0,0,0,0}, acc01={0,0,0,0}, acc10={0,0,0,0}, acc11={0,0,0,0};
  f32x4 acc20={0,0,0,0}, acc21={0,0,0,0}, acc30={0,0,0,0}, acc31={0,0,0,0};

  for (int k = tid; k < NSTEP; k += 256) sstab[k] = stab[k];

  auto stageW = [&](int g, int buf){
    const char* src = wbase + (size_t)g*16384 + wid*1024 + lane*16;
    char* dst = smem + buf*16384 + wid*1024;
    #pragma unroll
    for (int k = 0; k < 4; k++)
      gload16(src + k*4096, dst + k*4096);
  };

  short8 a0A,a1A,a2A,a3A, a0B,a1B,a2B,a3B;
  int acA = 0, acB = 0;

#define PREFA(s, A0_,A1_,A2_,A3_, AC) { \
    int sc_ = (s) < NSTEP ? (s) : NSTEP-1; \
    int4 EE = sstab[sc_]; \
    int ey_ = __builtin_amdgcn_readfirstlane(EE.y); \
    int ez_ = __builtin_amdgcn_readfirstlane(EE.z); \
    int ew_ = __builtin_amdgcn_readfirstlane(EE.w); \
    AC = ((s) < NSTEP) && (T0 >= ey_) && (T0 <= ez_); \
    int base_ = T0 - ey_ - 127; \
    int rowsM1_ = ez_ - ey_ + 1; \
    const short* gb = trb + (size_t)ew_ * 32; \
    if (base_ >= 0 && base_ + 255 <= rowsM1_){ \
      const short* p_ = gb + (size_t)base_*32 + voffA; \
      A0_ = *(const short8*)(p_); \
      A1_ = *(const short8*)(p_ + 512); \
      A2_ = *(const short8*)(p_ + 1024); \
      A3_ = *(const short8*)(p_ + 1536); \
    } else { \
      int rel = base_ + rowbase; \
      int r0_ = rel;      r0_ = r0_ < 0 ? 0 : (r0_ > rowsM1_ ? rowsM1_ : r0_); \
      int r1_ = rel + 16; r1_ = r1_ < 0 ? 0 : (r1_ > rowsM1_ ? rowsM1_ : r1_); \
      int r2_ = rel + 32; r2_ = r2_ < 0 ? 0 : (r2_ > rowsM1_ ? rowsM1_ : r2_); \
      int r3_ = rel + 48; r3_ = r3_ < 0 ? 0 : (r3_ > rowsM1_ ? rowsM1_ : r3_); \
      A0_ = *(const short8*)(gb + r0_*32 + chunkoff); \
      A1_ = *(const short8*)(gb + r1_*32 + chunkoff); \
      A2_ = *(const short8*)(gb + r2_*32 + chunkoff); \
      A3_ = *(const short8*)(gb + r3_*32 + chunkoff); } }

#define CONS(kk, cb, A0_,A1_,A2_,A3_, AC) if (AC){ \
    const short* wp = Wlds + (cb)*8192 + (kk)*1024 + offw; \
    short8 w0_ = *(const short8*)wp; \
    short8 w1_ = *(const short8*)(wp + 512); \
    acc00 = __builtin_amdgcn_mfma_f32_16x16x32_bf16(A0_, w0_, acc00, 0,0,0); \
    acc01 = __builtin_amdgcn_mfma_f32_16x16x32_bf16(A0_, w1_, acc01, 0,0,0); \
    acc10 = __builtin_amdgcn_mfma_f32_16x16x32_bf16(A1_, w0_, acc10, 0,0,0); \
    acc11 = __builtin_amdgcn_mfma_f32_16x16x32_bf16(A1_, w1_, acc11, 0,0,0); \
    acc20 = __builtin_amdgcn_mfma_f32_16x16x32_bf16(A2_, w0_, acc20, 0,0,0); \
    acc21 = __builtin_amdgcn_mfma_f32_16x16x32_bf16(A2_, w1_, acc21, 0,0,0); \
    acc30 = __builtin_amdgcn_mfma_f32_16x16x32_bf16(A3_, w0_, acc30, 0,0,0); \
    acc31 = __builtin_amdgcn_mfma_f32_16x16x32_bf16(A3_, w1_, acc31, 0,0,0); }

  stageW(0, 0);
  asm volatile("s_waitcnt vmcnt(0)" ::: "memory");
  __syncthreads();

  PREFA(0, a0A,a1A,a2A,a3A, acA)
  PREFA(1, a0B,a1B,a2B,a3B, acB)
  int cbuf = 0;
  for (int g = 0; g < NGRP; ++g){
    if (g + 1 < NGRP) stageW(g + 1, cbuf ^ 1);
    int sb = g*GSTEPS;
    #pragma unroll
    for (int k = 0; k < GSTEPS; k += 2){
      CONS(k,   cbuf, a0A,a1A,a2A,a3A, acA)
      PREFA(sb+k+2, a0A,a1A,a2A,a3A, acA)
      CONS(k+1, cbuf, a0B,a1B,a2B,a3B, acB)
      PREFA(sb+k+3, a0B,a1B,a2B,a3B, acB)
    }
    asm volatile("s_waitcnt vmcnt(8)" ::: "memory");
    __builtin_amdgcn_s_barrier();
    cbuf ^= 1;
  }

  {
    float* Ob = (float*)smem;
    int r0e = wid*64 + chunk*4;
    for (int r = 0; r < 4; r++){
      Ob[(r0e +  0 + r)*33 + rowlane]      = acc00[r];
      Ob[(r0e +  0 + r)*33 + rowlane + 16] = acc01[r];
      Ob[(r0e + 16 + r)*33 + rowlane]      = acc10[r];
      Ob[(r0e + 16 + r)*33 + rowlane + 16] = acc11[r];
      Ob[(r0e + 32 + r)*33 + rowlane]      = acc20[r];
      Ob[(r0e + 32 + r)*33 + rowlane + 16] = acc21[r];
      Ob[(r0e + 48 + r)*33 + rowlane]      = acc30[r];
      Ob[(r0e + 48 + r)*33 + rowlane + 16] = acc31[r];
    }
    __syncthreads();
    for (int r = 0; r < 32; r++){
      int flat = r*256 + tid;
      int o = flat >> 8, t = flat & 255;
      out[((size_t)(b*32 + o) << 14) + T0 + t] = Ob[t*33 + o];
    }
  }
}

// ================= launcher =================
extern "C" void kernel_launch(void* const* d_in, const int* in_sizes, int n_in,
                              void* d_out, int out_size, void* d_ws, size_t ws_size,
                              hipStream_t stream) {
  const float* x    = (const float*)d_in[0];
  const float* kern = (const float*)d_in[1];
  const float* cen  = (const float*)d_in[2];
  float* out = (float*)d_out;
  char* ws = (char*)d_ws;

  long tR = totRows();
  size_t oWts  = 4096;
  size_t wtsBytes = (size_t)NGRP * 16384;
  size_t oStab = (oWts + wtsBytes + 255) & ~(size_t)255;
  size_t oTmp  = (oStab + (size_t)NSTEP*16 + 1023) & ~(size_t)1023;
  size_t tmpBytes  = (size_t)8*32*256*12*8;
  size_t tmpTBytes = (size_t)8*32*3*8;
  size_t oTr   = (oTmp + tmpBytes + tmpTBytes + 1023) & ~(size_t)1023;

  size_t trB_per = (size_t)tR * 64;
  size_t sB_per  = (size_t)SROWS * 128;

  float* invn = (float*)ws;
  __hip_bfloat16* wts = (__hip_bfloat16*)(ws + oWts);
  int4* stab = (int4*)(ws + oStab);
  double* tmp  = (double*)(ws + oTmp);
  double* tmpT = (double*)(ws + oTmp + tmpBytes);
  __hip_bfloat16* tr = (__hip_bfloat16*)(ws + oTr);

  int CH = 0, SC = 1, DUP = 1;
  {
    int scs[7] = {8,4,4,2,2,1,1};
    int dps[7] = {1,2,1,2,1,2,1};
    for (int ci = 0; ci < 7; ci++){
      size_t need = oTr + 8*trB_per + (size_t)3*dps[ci]*scs[ci]*sB_per;
      if (need <= ws_size){ CH = 8; SC = scs[ci]; DUP = dps[ci]; break; }
    }
    if (CH == 0){
      int cc[5] = {4,4,2,2,1};
      int ss[5] = {4,2,2,1,1};
      for (int ci = 0; ci < 5; ci++){
        size_t need = oTr + (size_t)cc[ci]*trB_per + (size_t)3*ss[ci]*sB_per;
        if (need <= ws_size){ CH = cc[ci]; SC = ss[ci]; DUP = 1; break; }
      }
      if (CH == 0){ CH = 1; SC = 1; DUP = 1; }
    }
  }
  size_t oS = oTr + (size_t)CH * trB_per;
  auto S1p = [&](int p){ return (float*)(ws + oS + ((size_t)(0*DUP + p))*SC*sB_per); };
  auto S2p = [&](int p){ return (float*)(ws + oS + ((size_t)(1*DUP + p))*SC*sB_per); };
  auto R1p = [&](int p){ return (float*)(ws + oS + ((size_t)(2*DUP + p))*SC*sB_per); };

  if (CH == 8){
    int nch = 8 / SC;
    fuseA_k<<<8*P1T + 1024 + 2 + 256, 256, 0, stream>>>(x, kern, cen, invn, stab, tmp, tmpT, tr,
                                                        8*P1T, 1024, 256, 0, tR);
    fuseB_k<<<NSTEP + SC*128, 256, 0, stream>>>(kern, cen, invn, wts, x, tmp, tmpT,
                                                S1p(0), S2p(0), R1p(0), NSTEP, SC*128, 0);
    for (int k = 0; k < nch; k++){
      int pa = (DUP == 2) ? (k & 1) : 0;
      int pb = (DUP == 2) ? ((k + 1) & 1) : 0;
      bool nxt = (k + 1 < nch);
      if (DUP == 2 && nxt){
        fuseC_k<<<SC*G2T + SC*128, 256, 0, stream>>>(S1p(pa), S2p(pa), R1p(pa), tr, SC*G2T, k*SC, tR,
                                                     x, tmp, tmpT, S1p(pb), S2p(pb), R1p(pb),
                                                     SC*128, (k+1)*SC);
      } else {
        fuseC_k<<<SC*G2T, 256, 0, stream>>>(S1p(pa), S2p(pa), R1p(pa), tr, SC*G2T, k*SC, tR,
                                            x, tmp, tmpT, S1p(0), S2p(0), R1p(0), 0, 0);
        if (nxt)
          fuseB_k<<<SC*128, 256, 0, stream>>>(kern, cen, invn, wts, x, tmp, tmpT,
                                              S1p(0), S2p(0), R1p(0), 0, SC*128, (k+1)*SC);
      }
    }
    gemm11_k<<<8*64, 256, 0, stream>>>((const short*)tr, (const short*)wts, stab, out, 0, tR);
  } else {
    for (int b0 = 0; b0 < 8; b0 += CH){
      fuseA_k<<<CH*P1T + (b0 == 0 ? 1024 + 2 + 256 : 0), 256, 0, stream>>>(
          x, kern, cen, invn, stab, tmp, tmpT, tr,
          CH*P1T, b0 == 0 ? 1024 : 0, b0 == 0 ? 256 : 0, b0, tR);
      for (int s0 = 0; s0 < CH; s0 += SC){
        fuseB_k<<<(b0 == 0 && s0 == 0 ? NSTEP : 0) + SC*128, 256, 0, stream>>>(
            kern, cen, invn, wts, x, tmp, tmpT, S1p(0), S2p(0), R1p(0),
            (b0 == 0 && s0 == 0) ? NSTEP : 0, SC*128, b0 + s0);
        fuseC_k<<<SC*G2T, 256, 0, stream>>>(S1p(0), S2p(0), R1p(0), tr, SC*G2T, s0, tR,
                                            x, tmp, tmpT, S1p(0), S2p(0), R1p(0), 0, 0);
      }
      gemm11_k<<<CH*64, 256, 0, stream>>>((const short*)tr, (const short*)wts, stab, out, b0, tR);
    }
  }
}

// Round 18
// 476.597 us; speedup vs baseline: 1.0974x; 1.0974x over previous
//
#include <hip/hip_runtime.h>
#include <hip/hip_bf16.h>
#include <stdint.h>

#define SEQ    16384
#define NKL    11
#define NSTEP  467
#define GSTEPS 8
#define NGRP   ((NSTEP + GSTEPS - 1)/GSTEPS)   // 59
#define PAD    128
#define SNLO   1152
#define SNHI   17544
#define SROWS  (SNLO + SNHI)   // 18696
#define P1T    261
#define G2T    1104

typedef __attribute__((ext_vector_type(8))) short short8;
typedef __attribute__((ext_vector_type(4))) float f32x4;

__host__ __device__ inline int arrUlo(int a){
  if (a == 0) return 0;
  if (a <= 9) return -(2*(1<<a) - 1);
  int lv = (a <= 18) ? (a-9) : (a-18);
  return -((1<<lv) - 1);
}
__host__ __device__ inline int arrRowsP(int a){ return SEQ - arrUlo(a) + 2*PAD; }
__host__ __device__ inline long arrOff(int a){ long o=0; for (int k=0;k<a;k++) o += arrRowsP(k); return o; }
__host__ __device__ inline long totRows(){ return arrOff(28); }

__device__ inline float multf(int l){ return (float)(pow(0.5, (double)l/4096.0)*0.9 + 0.1); }
__device__ inline float Kv(const float* kern, int l, int g, int o, int i, int p){
  return kern[ (((size_t)((l*2 + g)*32 + o))*32 + i)*16 + p ];
}
__device__ inline ushort bfb(float v){
  return __builtin_bit_cast(ushort, __float2bfloat16(v));
}

struct Step { int arr; int c; int l; int g; int kidx; float coeff; };

__device__ inline Step decode(int st){
  Step r;
  if (st == 0){ r = {0, 0, 0, 0, 0, 1.f}; return r; }
  if (st < 17){ int p = st-1;  r = {0, 1+p,  0, 1, p, 1.f}; return r; }
  if (st < 33){ int p = st-17; r = {0, -1-p, 0, 0, p, 1.f}; return r; }
  if (st < 465){
    int t = st-33; int blk = t/24, k = t%24;
    int l = 1 + blk/2; int g = (blk & 1) ? 0 : 1;
    int s = 1<<l, hs = s>>1, off = 16*(s-1);
    float inv2s = 0.5f/(float)s;
    int arrT = l, arrB1 = 9+l, arrM = 18+l, arrH = (l==1) ? 0 : (8+l);
    if (k < 18){
      int p = k-1; int pp = p < 0 ? 0 : (p > 15 ? 15 : p);
      int c = g ? (1+off+p*s-hs) : (-off-p*s-3*hs);
      r = {arrT, c, l, g, pp, inv2s}; return r;
    }
    int kk = k-18;
    if (g){
      int c3 = 1+off-3*hs, c3h = 1+off-hs, c4 = 1+off+16*s+hs, c4h = 1+off+16*s;
      switch(kk){
        case 0: r = {arrM,  c3,  l, g, 0,  -2.f*inv2s}; return r;
        case 1: r = {arrB1, c3,  l, g, 0,  -inv2s}; return r;
        case 2: r = {arrH,  c3h, l, g, 0,  -1.f}; return r;
        case 3: r = {arrB1, c4,  l, g, 15, -(2.f*s-1.f)*inv2s}; return r;
        case 4: r = {arrM,  c4,  l, g, 15, +2.f*inv2s}; return r;
        default:r = {arrH,  c4h, l, g, 15, -1.f}; return r;
      }
    } else {
      int c3 = -off+hs, c3h = -off, c4 = -off-17*s-hs, c4h = -off-16*s-hs;
      switch(kk){
        case 0: r = {arrB1, c3,  l, g, 0,  -(2.f*s-1.f)*inv2s}; return r;
        case 1: r = {arrM,  c3,  l, g, 0,  +2.f*inv2s}; return r;
        case 2: r = {arrH,  c3h, l, g, 0,  -1.f}; return r;
        case 3: r = {arrM,  c4,  l, g, 15, -2.f*inv2s}; return r;
        case 4: r = {arrB1, c4,  l, g, 15, -inv2s}; return r;
        default:r = {arrH,  c4h, l, g, 15, -1.f}; return r;
      }
    }
  }
  if (st == 465){ r = {13, 16369, 10, 1, 0, 1.f}; return r; }
  r = {13, -16384, 10, 0, 0, 1.f}; return r;
}

// ================= device bodies =================

__device__ void normBody(const float* __restrict__ kern, const float* __restrict__ cen,
                         float* __restrict__ invn, int bid, int tid, char* shm){
  double* sred = (double*)shm;
  int o = bid >> 5, i = bid & 31;
  float mlt[NKL];
  for (int l = 0; l < NKL; l++) mlt[l] = multf(l);
  double acc = 0.0;
  for (int pos = tid; pos < 2*SEQ; pos += 256){
    int r = pos & (SEQ-1);
    int lr = (r >> 4) + 1;
    int l  = 31 - __clz(lr);
    int s  = 1 << l;
    int j  = r - 16*(s - 1);
    float c = (j + 0.5f)/(float)s - 0.5f;
    c = fminf(fmaxf(c, 0.f), 15.f);
    int i0 = (int)floorf(c);
    int i1 = (i0+1 < 15) ? i0+1 : 15;
    float w = c - (float)i0;
    int g = pos >> 14;
    float v = Kv(kern,l,g,o,i,i0)*(1.f-w) + Kv(kern,l,g,o,i,i1)*w;
    v *= mlt[l];
    acc += (double)v * v;
  }
  sred[tid] = acc; __syncthreads();
  for (int ofs = 128; ofs > 0; ofs >>= 1){ if (tid < ofs) sred[tid] += sred[tid+ofs]; __syncthreads(); }
  if (tid == 0){
    float cc = cen[o*32 + i];
    double tot = sred[0] + (double)cc*cc;
    invn[o*32 + i] = (float)(1.0 / sqrt(tot));
  }
}

__device__ void setupBody(int4* __restrict__ stab, int bid, int tid){
  int st = bid*256 + tid;
  if (st >= NSTEP) return;
  Step sp = decode(st);
  int ulo = arrUlo(sp.arr);
  long base = arrOff(sp.arr) + (sp.c - ulo) + PAD;
  int y = ulo - 255 - sp.c;
  stab[st] = make_int4((int)base, y, SEQ - 1 - sp.c, (int)(base + y + 127));
}

__device__ void wtsBody(const float* __restrict__ kern, const float* __restrict__ cen,
                        const float* __restrict__ invn, __hip_bfloat16* __restrict__ wts,
                        int st, int tid){
  Step sp = decode(st);
  float m = multf(sp.l);
  for (int idx = tid; idx < 1024; idx += 256){
    int o = idx >> 5, i = idx & 31;
    float in = invn[o*32 + i];
    float w;
    if (st == 0) w = cen[o*32 + i] * in;
    else         w = m * Kv(kern, sp.l, sp.g, o, i, sp.kidx) * in * sp.coeff;
    int sidx = idx ^ (((o >> 1) & 3) << 3);
    wts[(size_t)st*1024 + sidx] = __float2bfloat16(w);
  }
}

__device__ void pfsBody(const float* __restrict__ x, double* __restrict__ tmp,
                        double* __restrict__ tmpT, int bid, int tid, char* shm){
  double* sc1 = (double*)shm;
  double* sc2 = sc1 + 256;
  double* scr = sc2 + 256;
  double* tots = scr + 256;
  int b = bid >> 5, i = bid & 31;
  const float* xp = x + (((size_t)(b*32 + i)) << 14);
  int n0 = tid * 64;
  double lp = 0.0, lsum = 0.0, rsum = 0.0;
  for (int e = 0; e < 64; e++){
    double xv = (double)xp[n0 + e];
    lsum += lp;
    lp += xv;
    rsum += (double)(n0 + e) * xv;
  }
  sc1[tid] = lp; sc2[tid] = lsum; scr[tid] = rsum;
  __syncthreads();
  if (tid == 0){
    double a1 = 0, a2 = 0, ar = 0;
    for (int t = 0; t < 256; t++){
      double l1 = sc1[t], l2 = sc2[t], lr = scr[t];
      sc1[t] = a1; sc2[t] = a2; scr[t] = ar;
      a2 += 64.0*a1 + l2;
      a1 += l1;
      ar += lr;
    }
    tots[0] = a1; tots[1] = a2; tots[2] = ar;
  }
  __syncthreads();
  double s1v = sc1[tid], s2v = sc2[tid], r1v = scr[tid];
  double* tp = tmp + ((size_t)((b*32 + i)*256 + tid)) * 12;
  for (int e = 0; e < 64; e++){
    if ((e & 15) == 0){
      int q = e >> 4;
      tp[q*3+0] = s1v; tp[q*3+1] = s2v; tp[q*3+2] = r1v;
    }
    double xv = (double)xp[n0 + e];
    s2v += s1v; s1v += xv; r1v += (double)(n0 + e) * xv;
  }
  if (tid == 0){
    double* tt = tmpT + (size_t)(b*32 + i)*3;
    tt[0] = tots[0]; tt[1] = tots[1]; tt[2] = tots[2];
  }
}

__device__ void pfeBody(const float* __restrict__ x, const double* __restrict__ tmp,
                        const double* __restrict__ tmpT,
                        float* __restrict__ S1c, float* __restrict__ S2c, float* __restrict__ R1c,
                        int gb, int tid, int b0){
  int blocal = gb >> 7, bx = gb & 127;
  int i = tid & 31, sj = tid >> 5;
  int sub = bx*8 + sj;
  int b = b0 + blocal;
  const double* tp = tmp + ((size_t)((b*32 + i)*1024 + sub)) * 3;
  double s1v = tp[0], s2v = tp[1], r1v = tp[2];
  const float* xp = x + (((size_t)(b*32 + i)) << 14);
  float* o1 = S1c + (size_t)blocal * SROWS * 32 + i;
  float* o2 = S2c + (size_t)blocal * SROWS * 32 + i;
  float* o3 = R1c + (size_t)blocal * SROWS * 32 + i;
  int n0 = sub * 16;
  for (int e = 0; e < 16; e++){
    int n = n0 + e;
    size_t row = (size_t)(n + SNLO) * 32;
    o1[row] = (float)s1v; o2[row] = (float)s2v; o3[row] = (float)r1v;
    double xv = (double)xp[n];
    s2v += s1v; s1v += xv; r1v += (double)n * xv;
  }
  float* p1b = S1c + (size_t)blocal * SROWS * 32;
  float* p2b = S2c + (size_t)blocal * SROWS * 32;
  float* p3b = R1c + (size_t)blocal * SROWS * 32;
  int flat = bx*256 + tid;
  for (int idx = flat; idx < SNLO*32; idx += 32768){
    p1b[idx] = 0.f; p2b[idx] = 0.f; p3b[idx] = 0.f;
  }
  const double* tt = tmpT + (size_t)b*32*3;
  for (int idx = flat; idx < (SNHI-SEQ)*32; idx += 32768){
    int r = idx >> 5, ii = idx & 31;
    double T1 = tt[ii*3], T2 = tt[ii*3+1], TR = tt[ii*3+2];
    size_t ofs = (size_t)(SEQ + SNLO) * 32 + idx;
    p1b[ofs] = (float)T1;
    p2b[ofs] = (float)(T2 + (double)r * T1);
    p3b[ofs] = (float)TR;
  }
}

__device__ void p1Body(const float* __restrict__ x, __hip_bfloat16* __restrict__ tr,
                       int bid, int tid, char* shm, int b0, long tR){
  float* Xb = (float*)shm;
  float* Ab = Xb + 4096;
  float* Bb = Ab + 4096;
  float* Db = Bb + 4096;
  int bl = bid / P1T, bx = bid % P1T;
  int b = b0 + bl;
  int S0 = -192 + bx*64;
  ushort* trb = (ushort*)tr + (size_t)bl * tR * 32;

  {
    int i = tid >> 3, seg = tid & 7;
    const float* xp = x + (((size_t)(b*32 + i)) << 14);
    for (int e = 0; e < 16; e++){
      int ul = seg*16 + e; int u = S0 + ul;
      Xb[ul*32 + i] = (u >= 0 && u < SEQ) ? xp[u] : 0.f;
    }
  }
  __syncthreads();

  auto storeArr = [&](const float* src, int arr){
    int ulo = arrUlo(arr); long ofs = arrOff(arr);
    unsigned rows = (unsigned)(SEQ - ulo + 2*PAD);
    for (int e2 = 0; e2 < 4; e2++){
      int f2 = e2*256 + tid;
      int ul = f2 >> 4, j = (f2 & 15)*2;
      unsigned p = (unsigned)(S0 + ul - (ulo - PAD));
      if (p < rows){
        ushort2 pk;
        pk.x = bfb(src[ul*32 + j]);
        pk.y = bfb(src[ul*32 + j + 1]);
        *(ushort2*)(trb + ((size_t)(ofs + p))*32 + j) = pk;
      }
    }
  };
  auto storeT = [&](const float* nx, int arr){
    int ulo = arrUlo(arr); long ofs = arrOff(arr);
    unsigned rows = (unsigned)(SEQ - ulo + 2*PAD);
    for (int e2 = 0; e2 < 4; e2++){
      int f2 = e2*256 + tid;
      int ul = f2 >> 4, j = (f2 & 15)*2;
      unsigned p = (unsigned)(S0 + ul - (ulo - PAD));
      if (p < rows){
        ushort2 pk;
        pk.x = bfb(nx[ul*32 + j]     + nx[(ul+1)*32 + j]);
        pk.y = bfb(nx[ul*32 + j + 1] + nx[(ul+1)*32 + j + 1]);
        *(ushort2*)(trb + ((size_t)(ofs + p))*32 + j) = pk;
      }
    }
  };

  {
    const float* cur = Xb; float* nxt = Ab;
    #pragma unroll
    for (int l = 1; l <= 5; l++){
      int sp32 = (1 << (l-1)) * 32;
      int LIM = 130 - (2 << l);
      for (int e2 = 0; e2 < 16; e2++){
        int flat = e2*256 + tid;
        if ((flat >> 5) < LIM)
          nxt[flat] = cur[flat] + 2.f*cur[flat + sp32] + cur[flat + 2*sp32];
      }
      __syncthreads();
      storeT(nxt, l);
      cur = nxt; nxt = (l & 1) ? Bb : Ab;
    }
  }
  __syncthreads();
  {
    for (int e2 = 0; e2 < 16; e2++){
      int flat = e2*256 + tid;
      if ((flat >> 5) < 127){
        Ab[flat] = Xb[flat] + Xb[flat + 32];
        Db[flat] = Xb[flat + 32];
      }
    }
    __syncthreads();
    storeArr(Ab, 10); storeArr(Db, 19);
    float* bc = Ab; float* mc = Db; float* bn = Xb; float* mn = Bb;
    #pragma unroll
    for (int l = 2; l <= 5; l++){
      int sp = 1 << (l-1), sp32 = sp*32;
      int LIM = 129 - (1 << l);
      float fs = (float)sp;
      for (int e2 = 0; e2 < 16; e2++){
        int flat = e2*256 + tid;
        if ((flat >> 5) < LIM){
          float bwv = bc[flat + sp32];
          bn[flat] = bc[flat] + bwv;
          mn[flat] = mc[flat] + mc[flat + sp32] + fs*bwv;
        }
      }
      __syncthreads();
      storeArr(bn, 9 + l); storeArr(mn, 18 + l);
      float* t1 = bc; bc = bn; bn = t1;
      float* t2 = mc; mc = mn; mn = t2;
    }
  }
}

__device__ void gen2Body(const float* __restrict__ S1p, const float* __restrict__ S2p,
                         const float* __restrict__ R1p, __hip_bfloat16* __restrict__ tr,
                         int gb0, int nG, int tid, int s0, long tR){
  int gb = (gb0 & 7) * (nG >> 3) + (gb0 >> 3);
  int bl = gb / G2T, bx = gb - bl*G2T;
  int i = tid & 31, ug = tid >> 5;
  ushort* trb = (ushort*)tr + (size_t)(s0 + bl) * tR * 32;
  const float* s1 = S1p + (size_t)bl * SROWS * 32 + i;
  const float* s2 = S2p + (size_t)bl * SROWS * 32 + i;
  const float* r1 = R1p + (size_t)bl * SROWS * 32 + i;
  for (int e = 0; e < 2; e++){
    int u = -SNLO + bx*16 + e*8 + ug;
    size_t ns = (size_t)(u + SNLO) * 32;
    float s1_0 = s1[ns], s1_1 = s1[ns + 32];
    float s2_0 = s2[ns], s2_1 = s2[ns + 32];
    float r1_0 = r1[ns];
    {
      unsigned p = (unsigned)(u + PAD);
      if (p < (unsigned)(SEQ + 2*PAD))
        trb[((size_t)(arrOff(0) + p))*32 + i] = bfb(s1_1 - s1_0);
    }
    #pragma unroll
    for (int li = 0; li < 4; li++){
      const int l = 6 + li;
      const int s = 1 << l;
      float sa = s2[ns + (size_t)s*32],      sb = s2[ns + (size_t)(s+1)*32];
      float sc2 = s2[ns + (size_t)(2*s)*32], sd = s2[ns + (size_t)(2*s+1)*32];
      float Tv = (sc2 + sd) - 2.f*(sa + sb) + (s2_0 + s2_1);
      float b1v = s1[ns + (size_t)s*32] - s1_0;
      float mv  = (r1[ns + (size_t)s*32] - r1_0) - (float)u * b1v;
      {
        int ulo = -(2*s - 1);
        unsigned p = (unsigned)(u - (ulo - PAD));
        if (p < (unsigned)(SEQ - ulo + 2*PAD))
          trb[((size_t)(arrOff(l) + p))*32 + i] = bfb(Tv);
      }
      {
        int ulo = -(s - 1);
        unsigned p = (unsigned)(u - (ulo - PAD));
        unsigned rows = (unsigned)(SEQ - ulo + 2*PAD);
        if (p < rows){
          trb[((size_t)(arrOff(9 + l) + p))*32 + i]  = bfb(b1v);
          trb[((size_t)(arrOff(18 + l) + p))*32 + i] = bfb(mv);
        }
      }
    }
  }
}

// ================= fused kernels =================

__global__ __launch_bounds__(256) void fuseA_k(const float* __restrict__ x,
                                               const float* __restrict__ kern,
                                               const float* __restrict__ cen,
                                               float* __restrict__ invn,
                                               int4* __restrict__ stab,
                                               double* __restrict__ tmp,
                                               double* __restrict__ tmpT,
                                               __hip_bfloat16* __restrict__ tr,
                                               int nP1, int nNorm, int nPfs, int b0, long tR){
  __shared__ __align__(16) char shm[65536];
  int bid = blockIdx.x, tid = threadIdx.x;
  if (bid < nP1){ p1Body(x, tr, bid, tid, shm, b0, tR); return; }
  bid -= nP1;
  if (bid < nNorm){ normBody(kern, cen, invn, bid, tid, shm); return; }
  bid -= nNorm;
  if (nNorm > 0 && bid < 2){ setupBody(stab, bid, tid); return; }
  if (nNorm > 0) bid -= 2;
  if (bid < nPfs) pfsBody(x, tmp, tmpT, bid, tid, shm);
}

__global__ __launch_bounds__(256) void fuseB_k(const float* __restrict__ kern,
                                               const float* __restrict__ cen,
                                               const float* __restrict__ invn,
                                               __hip_bfloat16* __restrict__ wts,
                                               const float* __restrict__ x,
                                               const double* __restrict__ tmp,
                                               const double* __restrict__ tmpT,
                                               float* __restrict__ S1c, float* __restrict__ S2c,
                                               float* __restrict__ R1c,
                                               int nWts, int nPfe, int b0){
  int bid = blockIdx.x, tid = threadIdx.x;
  if (bid < nWts){ wtsBody(kern, cen, invn, wts, bid, tid); return; }
  bid -= nWts;
  if (bid < nPfe) pfeBody(x, tmp, tmpT, S1c, S2c, R1c, bid, tid, b0);
}

__global__ __launch_bounds__(256) void fuseC_k(const float* __restrict__ S1a,
                                               const float* __restrict__ S2a,
                                               const float* __restrict__ R1a,
                                               __hip_bfloat16* __restrict__ tr,
                                               int nGen2, int s0g, long tR,
                                               const float* __restrict__ x,
                                               const double* __restrict__ tmp,
                                               const double* __restrict__ tmpT,
                                               float* __restrict__ S1b, float* __restrict__ S2b,
                                               float* __restrict__ R1b,
                                               int nPfe, int b0p){
  int bid = blockIdx.x, tid = threadIdx.x;
  if (bid < nGen2){ gen2Body(S1a, S2a, R1a, tr, bid, nGen2, tid, s0g, tR); return; }
  bid -= nGen2;
  if (bid < nPfe) pfeBody(x, tmp, tmpT, S1b, S2b, R1b, bid, tid, b0p);
}

// ================= GEMM: 4-deep A register pipeline =================
__device__ inline void gload16(const void* g, void* l){
  __builtin_amdgcn_global_load_lds(
      (const __attribute__((address_space(1))) void*)g,
      (__attribute__((address_space(3))) void*)l, 16, 0, 0);
}

__global__ __launch_bounds__(256) void gemm12_k(const short* __restrict__ tr,
                                                const short* __restrict__ wts,
                                                const int4* __restrict__ stab,
                                                float* __restrict__ out,
                                                int b0, long tR){
  __shared__ int4 sstab[NSTEP];
  __shared__ __align__(16) char smem[33792];
  short* Wlds = (short*)smem;
  int tid = threadIdx.x, wid = tid >> 6, lane = tid & 63;
  int N = gridDim.x;
  int wg = (blockIdx.x & 7) * (N >> 3) + (blockIdx.x >> 3);
  int bl = wg >> 6, T0 = (wg & 63) << 8;
  int b = b0 + bl;
  int rowlane = lane & 15, chunk = lane >> 4;
  const short* trb = tr + (size_t)bl * tR * 32;
  const char* wbase = (const char*)wts;
  int rowbase = wid*64 + rowlane;
  int chunkoff = chunk*8;
  int voffA = rowbase*32 + chunkoff;
  int offw = (rowlane*32 + chunk*8) ^ (((rowlane >> 1) & 3) << 3);
  f32x4 acc00={0,0,0,0}, acc01={0,0,0,0}, acc10={0,0,0,0}, acc11={0,0,0,0};
  f32x4 acc20={0,0,0,0}, acc21={0,0,0,0}, acc30={0,0,0,0}, acc31={0,0,0,0};

  for (int k = tid; k < NSTEP; k += 256) sstab[k] = stab[k];

  auto stageW = [&](int g, int buf){
    const char* src = wbase + (size_t)g*16384 + wid*1024 + lane*16;
    char* dst = smem + buf*16384 + wid*1024;
    #pragma unroll
    for (int k = 0; k < 4; k++)
      gload16(src + k*4096, dst + k*4096);
  };

  short8 a0A,a1A,a2A,a3A, a0B,a1B,a2B,a3B;
  short8 a0C,a1C,a2C,a3C, a0D,a1D,a2D,a3D;
  int acA = 0, acB = 0, acC = 0, acD = 0;

#define PREFA(s, A0_,A1_,A2_,A3_, AC) { \
    int sc_ = (s) < NSTEP ? (s) : NSTEP-1; \
    int4 EE = sstab[sc_]; \
    int ey_ = __builtin_amdgcn_readfirstlane(EE.y); \
    int ez_ = __builtin_amdgcn_readfirstlane(EE.z); \
    int ew_ = __builtin_amdgcn_readfirstlane(EE.w); \
    AC = ((s) < NSTEP) && (T0 >= ey_) && (T0 <= ez_); \
    int base_ = T0 - ey_ - 127; \
    int rowsM1_ = ez_ - ey_ + 1; \
    const short* gb = trb + (size_t)ew_ * 32; \
    if (base_ >= 0 && base_ + 255 <= rowsM1_){ \
      const short* p_ = gb + (size_t)base_*32 + voffA; \
      A0_ = *(const short8*)(p_); \
      A1_ = *(const short8*)(p_ + 512); \
      A2_ = *(const short8*)(p_ + 1024); \
      A3_ = *(const short8*)(p_ + 1536); \
    } else { \
      int rel = base_ + rowbase; \
      int r0_ = rel;      r0_ = r0_ < 0 ? 0 : (r0_ > rowsM1_ ? rowsM1_ : r0_); \
      int r1_ = rel + 16; r1_ = r1_ < 0 ? 0 : (r1_ > rowsM1_ ? rowsM1_ : r1_); \
      int r2_ = rel + 32; r2_ = r2_ < 0 ? 0 : (r2_ > rowsM1_ ? rowsM1_ : r2_); \
      int r3_ = rel + 48; r3_ = r3_ < 0 ? 0 : (r3_ > rowsM1_ ? rowsM1_ : r3_); \
      A0_ = *(const short8*)(gb + r0_*32 + chunkoff); \
      A1_ = *(const short8*)(gb + r1_*32 + chunkoff); \
      A2_ = *(const short8*)(gb + r2_*32 + chunkoff); \
      A3_ = *(const short8*)(gb + r3_*32 + chunkoff); } }

#define CONS(kk, cb, A0_,A1_,A2_,A3_, AC) if (AC){ \
    const short* wp = Wlds + (cb)*8192 + (kk)*1024 + offw; \
    short8 w0_ = *(const short8*)wp; \
    short8 w1_ = *(const short8*)(wp + 512); \
    acc00 = __builtin_amdgcn_mfma_f32_16x16x32_bf16(A0_, w0_, acc00, 0,0,0); \
    acc01 = __builtin_amdgcn_mfma_f32_16x16x32_bf16(A0_, w1_, acc01, 0,0,0); \
    acc10 = __builtin_amdgcn_mfma_f32_16x16x32_bf16(A1_, w0_, acc10, 0,0,0); \
    acc11 = __builtin_amdgcn_mfma_f32_16x16x32_bf16(A1_, w1_, acc11, 0,0,0); \
    acc20 = __builtin_amdgcn_mfma_f32_16x16x32_bf16(A2_, w0_, acc20, 0,0,0); \
    acc21 = __builtin_amdgcn_mfma_f32_16x16x32_bf16(A2_, w1_, acc21, 0,0,0); \
    acc30 = __builtin_amdgcn_mfma_f32_16x16x32_bf16(A3_, w0_, acc30, 0,0,0); \
    acc31 = __builtin_amdgcn_mfma_f32_16x16x32_bf16(A3_, w1_, acc31, 0,0,0); }

  stageW(0, 0);
  asm volatile("s_waitcnt vmcnt(0)" ::: "memory");
  __syncthreads();

  PREFA(0, a0A,a1A,a2A,a3A, acA)
  PREFA(1, a0B,a1B,a2B,a3B, acB)
  PREFA(2, a0C,a1C,a2C,a3C, acC)
  PREFA(3, a0D,a1D,a2D,a3D, acD)
  int cbuf = 0;
  for (int g = 0; g < NGRP; ++g){
    if (g + 1 < NGRP) stageW(g + 1, cbuf ^ 1);
    int sb = g*GSTEPS;
    #pragma unroll
    for (int k = 0; k < GSTEPS; k += 4){
      CONS(k,   cbuf, a0A,a1A,a2A,a3A, acA)
      PREFA(sb+k+4, a0A,a1A,a2A,a3A, acA)
      CONS(k+1, cbuf, a0B,a1B,a2B,a3B, acB)
      PREFA(sb+k+5, a0B,a1B,a2B,a3B, acB)
      CONS(k+2, cbuf, a0C,a1C,a2C,a3C, acC)
      PREFA(sb+k+6, a0C,a1C,a2C,a3C, acC)
      CONS(k+3, cbuf, a0D,a1D,a2D,a3D, acD)
      PREFA(sb+k+7, a0D,a1D,a2D,a3D, acD)
    }
    // retire stageW(g+1) (in-order vmcnt); keep the 4 newest PREFAs (16 ops) in flight
    asm volatile("s_waitcnt vmcnt(16)" ::: "memory");
    __builtin_amdgcn_s_barrier();
    cbuf ^= 1;
  }

  {
    float* Ob = (float*)smem;
    int r0e = wid*64 + chunk*4;
    for (int r = 0; r < 4; r++){
      Ob[(r0e +  0 + r)*33 + rowlane]      = acc00[r];
      Ob[(r0e +  0 + r)*33 + rowlane + 16] = acc01[r];
      Ob[(r0e + 16 + r)*33 + rowlane]      = acc10[r];
      Ob[(r0e + 16 + r)*33 + rowlane + 16] = acc11[r];
      Ob[(r0e + 32 + r)*33 + rowlane]      = acc20[r];
      Ob[(r0e + 32 + r)*33 + rowlane + 16] = acc21[r];
      Ob[(r0e + 48 + r)*33 + rowlane]      = acc30[r];
      Ob[(r0e + 48 + r)*33 + rowlane + 16] = acc31[r];
    }
    __syncthreads();
    for (int r = 0; r < 32; r++){
      int flat = r*256 + tid;
      int o = flat >> 8, t = flat & 255;
      out[((size_t)(b*32 + o) << 14) + T0 + t] = Ob[t*33 + o];
    }
  }
}

// ================= launcher =================
extern "C" void kernel_launch(void* const* d_in, const int* in_sizes, int n_in,
                              void* d_out, int out_size, void* d_ws, size_t ws_size,
                              hipStream_t stream) {
  const float* x    = (const float*)d_in[0];
  const float* kern = (const float*)d_in[1];
  const float* cen  = (const float*)d_in[2];
  float* out = (float*)d_out;
  char* ws = (char*)d_ws;

  long tR = totRows();
  size_t oWts  = 4096;
  size_t wtsBytes = (size_t)NGRP * 16384;
  size_t oStab = (oWts + wtsBytes + 255) & ~(size_t)255;
  size_t oTmp  = (oStab + (size_t)NSTEP*16 + 1023) & ~(size_t)1023;
  size_t tmpBytes  = (size_t)8*32*256*12*8;
  size_t tmpTBytes = (size_t)8*32*3*8;
  size_t oTr   = (oTmp + tmpBytes + tmpTBytes + 1023) & ~(size_t)1023;

  size_t trB_per = (size_t)tR * 64;
  size_t sB_per  = (size_t)SROWS * 128;

  float* invn = (float*)ws;
  __hip_bfloat16* wts = (__hip_bfloat16*)(ws + oWts);
  int4* stab = (int4*)(ws + oStab);
  double* tmp  = (double*)(ws + oTmp);
  double* tmpT = (double*)(ws + oTmp + tmpBytes);
  __hip_bfloat16* tr = (__hip_bfloat16*)(ws + oTr);

  int CH = 0, SC = 1, DUP = 1;
  {
    int scs[7] = {8,4,4,2,2,1,1};
    int dps[7] = {1,2,1,2,1,2,1};
    for (int ci = 0; ci < 7; ci++){
      size_t need = oTr + 8*trB_per + (size_t)3*dps[ci]*scs[ci]*sB_per;
      if (need <= ws_size){ CH = 8; SC = scs[ci]; DUP = dps[ci]; break; }
    }
    if (CH == 0){
      int cc[5] = {4,4,2,2,1};
      int ss[5] = {4,2,2,1,1};
      for (int ci = 0; ci < 5; ci++){
        size_t need = oTr + (size_t)cc[ci]*trB_per + (size_t)3*ss[ci]*sB_per;
        if (need <= ws_size){ CH = cc[ci]; SC = ss[ci]; DUP = 1; break; }
      }
      if (CH == 0){ CH = 1; SC = 1; DUP = 1; }
    }
  }
  size_t oS = oTr + (size_t)CH * trB_per;
  auto S1p = [&](int p){ return (float*)(ws + oS + ((size_t)(0*DUP + p))*SC*sB_per); };
  auto S2p = [&](int p){ return (float*)(ws + oS + ((size_t)(1*DUP + p))*SC*sB_per); };
  auto R1p = [&](int p){ return (float*)(ws + oS + ((size_t)(2*DUP + p))*SC*sB_per); };

  if (CH == 8){
    int nch = 8 / SC;
    fuseA_k<<<8*P1T + 1024 + 2 + 256, 256, 0, stream>>>(x, kern, cen, invn, stab, tmp, tmpT, tr,
                                                        8*P1T, 1024, 256, 0, tR);
    fuseB_k<<<NSTEP + SC*128, 256, 0, stream>>>(kern, cen, invn, wts, x, tmp, tmpT,
                                                S1p(0), S2p(0), R1p(0), NSTEP, SC*128, 0);
    for (int k = 0; k < nch; k++){
      int pa = (DUP == 2) ? (k & 1) : 0;
      int pb = (DUP == 2) ? ((k + 1) & 1) : 0;
      bool nxt = (k + 1 < nch);
      if (DUP == 2 && nxt){
        fuseC_k<<<SC*G2T + SC*128, 256, 0, stream>>>(S1p(pa), S2p(pa), R1p(pa), tr, SC*G2T, k*SC, tR,
                                                     x, tmp, tmpT, S1p(pb), S2p(pb), R1p(pb),
                                                     SC*128, (k+1)*SC);
      } else {
        fuseC_k<<<SC*G2T, 256, 0, stream>>>(S1p(pa), S2p(pa), R1p(pa), tr, SC*G2T, k*SC, tR,
                                            x, tmp, tmpT, S1p(0), S2p(0), R1p(0), 0, 0);
        if (nxt)
          fuseB_k<<<SC*128, 256, 0, stream>>>(kern, cen, invn, wts, x, tmp, tmpT,
                                              S1p(0), S2p(0), R1p(0), 0, SC*128, (k+1)*SC);
      }
    }
    gemm12_k<<<8*64, 256, 0, stream>>>((const short*)tr, (const short*)wts, stab, out, 0, tR);
  } else {
    for (int b0 = 0; b0 < 8; b0 += CH){
      fuseA_k<<<CH*P1T + (b0 == 0 ? 1024 + 2 + 256 : 0), 256, 0, stream>>>(
          x, kern, cen, invn, stab, tmp, tmpT, tr,
          CH*P1T, b0 == 0 ? 1024 : 0, b0 == 0 ? 256 : 0, b0, tR);
      for (int s0 = 0; s0 < CH; s0 += SC){
        fuseB_k<<<(b0 == 0 && s0 == 0 ? NSTEP : 0) + SC*128, 256, 0, stream>>>(
            kern, cen, invn, wts, x, tmp, tmpT, S1p(0), S2p(0), R1p(0),
            (b0 == 0 && s0 == 0) ? NSTEP : 0, SC*128, b0 + s0);
        fuseC_k<<<SC*G2T, 256, 0, stream>>>(S1p(0), S2p(0), R1p(0), tr, SC*G2T, s0, tR,
                                            x, tmp, tmpT, S1p(0), S2p(0), R1p(0), 0, 0);
      }
      gemm12_k<<<CH*64, 256, 0, stream>>>((const short*)tr, (const short*)wts, stab, out, b0, tR);
    }
  }
}

// Round 19
// 467.382 us; speedup vs baseline: 1.1191x; 1.0197x over previous
//
#include <hip/hip_runtime.h>
#include <hip/hip_bf16.h>
#include <stdint.h>

#define SEQ    16384
#define NKL    11
#define NSTEP  467
#define GSTEPS 8
#define NGRP   ((NSTEP + GSTEPS - 1)/GSTEPS)   // 59
#define PAD    128
#define SNLO   1152
#define SNHI   17544
#define SROWS  (SNLO + SNHI)   // 18696
#define P1T    261
#define G2T    1104

typedef __attribute__((ext_vector_type(8))) short short8;
typedef __attribute__((ext_vector_type(4))) float f32x4;

__host__ __device__ inline int arrUlo(int a){
  if (a == 0) return 0;
  if (a <= 9) return -(2*(1<<a) - 1);
  int lv = (a <= 18) ? (a-9) : (a-18);
  return -((1<<lv) - 1);
}
__host__ __device__ inline int arrRowsP(int a){ return SEQ - arrUlo(a) + 2*PAD; }
__host__ __device__ inline long arrOff(int a){ long o=0; for (int k=0;k<a;k++) o += arrRowsP(k); return o; }
__host__ __device__ inline long totRows(){ return arrOff(28); }

__device__ inline float multf(int l){ return (float)(pow(0.5, (double)l/4096.0)*0.9 + 0.1); }
__device__ inline float Kv(const float* kern, int l, int g, int o, int i, int p){
  return kern[ (((size_t)((l*2 + g)*32 + o))*32 + i)*16 + p ];
}
__device__ inline ushort bfb(float v){
  return __builtin_bit_cast(ushort, __float2bfloat16(v));
}

struct Step { int arr; int c; int l; int g; int kidx; float coeff; };

__device__ inline Step decode(int st){
  Step r;
  if (st == 0){ r = {0, 0, 0, 0, 0, 1.f}; return r; }
  if (st < 17){ int p = st-1;  r = {0, 1+p,  0, 1, p, 1.f}; return r; }
  if (st < 33){ int p = st-17; r = {0, -1-p, 0, 0, p, 1.f}; return r; }
  if (st < 465){
    int t = st-33; int blk = t/24, k = t%24;
    int l = 1 + blk/2; int g = (blk & 1) ? 0 : 1;
    int s = 1<<l, hs = s>>1, off = 16*(s-1);
    float inv2s = 0.5f/(float)s;
    int arrT = l, arrB1 = 9+l, arrM = 18+l, arrH = (l==1) ? 0 : (8+l);
    if (k < 18){
      int p = k-1; int pp = p < 0 ? 0 : (p > 15 ? 15 : p);
      int c = g ? (1+off+p*s-hs) : (-off-p*s-3*hs);
      r = {arrT, c, l, g, pp, inv2s}; return r;
    }
    int kk = k-18;
    if (g){
      int c3 = 1+off-3*hs, c3h = 1+off-hs, c4 = 1+off+16*s+hs, c4h = 1+off+16*s;
      switch(kk){
        case 0: r = {arrM,  c3,  l, g, 0,  -2.f*inv2s}; return r;
        case 1: r = {arrB1, c3,  l, g, 0,  -inv2s}; return r;
        case 2: r = {arrH,  c3h, l, g, 0,  -1.f}; return r;
        case 3: r = {arrB1, c4,  l, g, 15, -(2.f*s-1.f)*inv2s}; return r;
        case 4: r = {arrM,  c4,  l, g, 15, +2.f*inv2s}; return r;
        default:r = {arrH,  c4h, l, g, 15, -1.f}; return r;
      }
    } else {
      int c3 = -off+hs, c3h = -off, c4 = -off-17*s-hs, c4h = -off-16*s-hs;
      switch(kk){
        case 0: r = {arrB1, c3,  l, g, 0,  -(2.f*s-1.f)*inv2s}; return r;
        case 1: r = {arrM,  c3,  l, g, 0,  +2.f*inv2s}; return r;
        case 2: r = {arrH,  c3h, l, g, 0,  -1.f}; return r;
        case 3: r = {arrM,  c4,  l, g, 15, -2.f*inv2s}; return r;
        case 4: r = {arrB1, c4,  l, g, 15, -inv2s}; return r;
        default:r = {arrH,  c4h, l, g, 15, -1.f}; return r;
      }
    }
  }
  if (st == 465){ r = {13, 16369, 10, 1, 0, 1.f}; return r; }
  r = {13, -16384, 10, 0, 0, 1.f}; return r;
}

// ================= device bodies =================

__device__ void normBody(const float* __restrict__ kern, const float* __restrict__ cen,
                         float* __restrict__ invn, int bid, int tid, char* shm){
  double* sred = (double*)shm;
  int o = bid >> 5, i = bid & 31;
  float mlt[NKL];
  for (int l = 0; l < NKL; l++) mlt[l] = multf(l);
  double acc = 0.0;
  for (int pos = tid; pos < 2*SEQ; pos += 256){
    int r = pos & (SEQ-1);
    int lr = (r >> 4) + 1;
    int l  = 31 - __clz(lr);
    int s  = 1 << l;
    int j  = r - 16*(s - 1);
    float c = (j + 0.5f)/(float)s - 0.5f;
    c = fminf(fmaxf(c, 0.f), 15.f);
    int i0 = (int)floorf(c);
    int i1 = (i0+1 < 15) ? i0+1 : 15;
    float w = c - (float)i0;
    int g = pos >> 14;
    float v = Kv(kern,l,g,o,i,i0)*(1.f-w) + Kv(kern,l,g,o,i,i1)*w;
    v *= mlt[l];
    acc += (double)v * v;
  }
  sred[tid] = acc; __syncthreads();
  for (int ofs = 128; ofs > 0; ofs >>= 1){ if (tid < ofs) sred[tid] += sred[tid+ofs]; __syncthreads(); }
  if (tid == 0){
    float cc = cen[o*32 + i];
    double tot = sred[0] + (double)cc*cc;
    invn[o*32 + i] = (float)(1.0 / sqrt(tot));
  }
}

__device__ void setupBody(int4* __restrict__ stab, int bid, int tid){
  int st = bid*256 + tid;
  if (st >= NSTEP) return;
  Step sp = decode(st);
  int ulo = arrUlo(sp.arr);
  long base = arrOff(sp.arr) + (sp.c - ulo) + PAD;
  int y = ulo - 255 - sp.c;
  stab[st] = make_int4((int)base, y, SEQ - 1 - sp.c, (int)(base + y + 127));
}

__device__ void wtsBody(const float* __restrict__ kern, const float* __restrict__ cen,
                        const float* __restrict__ invn, __hip_bfloat16* __restrict__ wts,
                        int st, int tid){
  Step sp = decode(st);
  float m = multf(sp.l);
  for (int idx = tid; idx < 1024; idx += 256){
    int o = idx >> 5, i = idx & 31;
    float in = invn[o*32 + i];
    float w;
    if (st == 0) w = cen[o*32 + i] * in;
    else         w = m * Kv(kern, sp.l, sp.g, o, i, sp.kidx) * in * sp.coeff;
    int sidx = idx ^ (((o >> 1) & 3) << 3);
    wts[(size_t)st*1024 + sidx] = __float2bfloat16(w);
  }
}

__device__ void pfsBody(const float* __restrict__ x, double* __restrict__ tmp,
                        double* __restrict__ tmpT, int bid, int tid, char* shm){
  double* sc1 = (double*)shm;
  double* sc2 = sc1 + 256;
  double* scr = sc2 + 256;
  double* tots = scr + 256;
  int b = bid >> 5, i = bid & 31;
  const float* xp = x + (((size_t)(b*32 + i)) << 14);
  int n0 = tid * 64;
  double lp = 0.0, lsum = 0.0, rsum = 0.0;
  for (int e = 0; e < 64; e++){
    double xv = (double)xp[n0 + e];
    lsum += lp;
    lp += xv;
    rsum += (double)(n0 + e) * xv;
  }
  sc1[tid] = lp; sc2[tid] = lsum; scr[tid] = rsum;
  __syncthreads();
  if (tid == 0){
    double a1 = 0, a2 = 0, ar = 0;
    for (int t = 0; t < 256; t++){
      double l1 = sc1[t], l2 = sc2[t], lr = scr[t];
      sc1[t] = a1; sc2[t] = a2; scr[t] = ar;
      a2 += 64.0*a1 + l2;
      a1 += l1;
      ar += lr;
    }
    tots[0] = a1; tots[1] = a2; tots[2] = ar;
  }
  __syncthreads();
  double s1v = sc1[tid], s2v = sc2[tid], r1v = scr[tid];
  double* tp = tmp + ((size_t)((b*32 + i)*256 + tid)) * 12;
  for (int e = 0; e < 64; e++){
    if ((e & 15) == 0){
      int q = e >> 4;
      tp[q*3+0] = s1v; tp[q*3+1] = s2v; tp[q*3+2] = r1v;
    }
    double xv = (double)xp[n0 + e];
    s2v += s1v; s1v += xv; r1v += (double)(n0 + e) * xv;
  }
  if (tid == 0){
    double* tt = tmpT + (size_t)(b*32 + i)*3;
    tt[0] = tots[0]; tt[1] = tots[1]; tt[2] = tots[2];
  }
}

__device__ void pfeBody(const float* __restrict__ x, const double* __restrict__ tmp,
                        const double* __restrict__ tmpT,
                        float* __restrict__ S1c, float* __restrict__ S2c, float* __restrict__ R1c,
                        int gb, int tid, int b0){
  int blocal = gb >> 7, bx = gb & 127;
  int i = tid & 31, sj = tid >> 5;
  int sub = bx*8 + sj;
  int b = b0 + blocal;
  const double* tp = tmp + ((size_t)((b*32 + i)*1024 + sub)) * 3;
  double s1v = tp[0], s2v = tp[1], r1v = tp[2];
  const float* xp = x + (((size_t)(b*32 + i)) << 14);
  float* o1 = S1c + (size_t)blocal * SROWS * 32 + i;
  float* o2 = S2c + (size_t)blocal * SROWS * 32 + i;
  float* o3 = R1c + (size_t)blocal * SROWS * 32 + i;
  int n0 = sub * 16;
  for (int e = 0; e < 16; e++){
    int n = n0 + e;
    size_t row = (size_t)(n + SNLO) * 32;
    o1[row] = (float)s1v; o2[row] = (float)s2v; o3[row] = (float)r1v;
    double xv = (double)xp[n];
    s2v += s1v; s1v += xv; r1v += (double)n * xv;
  }
  float* p1b = S1c + (size_t)blocal * SROWS * 32;
  float* p2b = S2c + (size_t)blocal * SROWS * 32;
  float* p3b = R1c + (size_t)blocal * SROWS * 32;
  int flat = bx*256 + tid;
  for (int idx = flat; idx < SNLO*32; idx += 32768){
    p1b[idx] = 0.f; p2b[idx] = 0.f; p3b[idx] = 0.f;
  }
  const double* tt = tmpT + (size_t)b*32*3;
  for (int idx = flat; idx < (SNHI-SEQ)*32; idx += 32768){
    int r = idx >> 5, ii = idx & 31;
    double T1 = tt[ii*3], T2 = tt[ii*3+1], TR = tt[ii*3+2];
    size_t ofs = (size_t)(SEQ + SNLO) * 32 + idx;
    p1b[ofs] = (float)T1;
    p2b[ofs] = (float)(T2 + (double)r * T1);
    p3b[ofs] = (float)TR;
  }
}

__device__ void p1Body(const float* __restrict__ x, __hip_bfloat16* __restrict__ tr,
                       int bid, int tid, char* shm, int b0, long tR){
  float* Xb = (float*)shm;
  float* Ab = Xb + 4096;
  float* Bb = Ab + 4096;
  float* Db = Bb + 4096;
  int bl = bid / P1T, bx = bid % P1T;
  int b = b0 + bl;
  int S0 = -192 + bx*64;
  ushort* trb = (ushort*)tr + (size_t)bl * tR * 32;

  {
    int i = tid >> 3, seg = tid & 7;
    const float* xp = x + (((size_t)(b*32 + i)) << 14);
    for (int e = 0; e < 16; e++){
      int ul = seg*16 + e; int u = S0 + ul;
      Xb[ul*32 + i] = (u >= 0 && u < SEQ) ? xp[u] : 0.f;
    }
  }
  __syncthreads();

  auto storeArr = [&](const float* src, int arr){
    int ulo = arrUlo(arr); long ofs = arrOff(arr);
    unsigned rows = (unsigned)(SEQ - ulo + 2*PAD);
    for (int e2 = 0; e2 < 4; e2++){
      int f2 = e2*256 + tid;
      int ul = f2 >> 4, j = (f2 & 15)*2;
      unsigned p = (unsigned)(S0 + ul - (ulo - PAD));
      if (p < rows){
        ushort2 pk;
        pk.x = bfb(src[ul*32 + j]);
        pk.y = bfb(src[ul*32 + j + 1]);
        *(ushort2*)(trb + ((size_t)(ofs + p))*32 + j) = pk;
      }
    }
  };
  auto storeT = [&](const float* nx, int arr){
    int ulo = arrUlo(arr); long ofs = arrOff(arr);
    unsigned rows = (unsigned)(SEQ - ulo + 2*PAD);
    for (int e2 = 0; e2 < 4; e2++){
      int f2 = e2*256 + tid;
      int ul = f2 >> 4, j = (f2 & 15)*2;
      unsigned p = (unsigned)(S0 + ul - (ulo - PAD));
      if (p < rows){
        ushort2 pk;
        pk.x = bfb(nx[ul*32 + j]     + nx[(ul+1)*32 + j]);
        pk.y = bfb(nx[ul*32 + j + 1] + nx[(ul+1)*32 + j + 1]);
        *(ushort2*)(trb + ((size_t)(ofs + p))*32 + j) = pk;
      }
    }
  };

  {
    const float* cur = Xb; float* nxt = Ab;
    #pragma unroll
    for (int l = 1; l <= 5; l++){
      int sp32 = (1 << (l-1)) * 32;
      int LIM = 130 - (2 << l);
      for (int e2 = 0; e2 < 16; e2++){
        int flat = e2*256 + tid;
        if ((flat >> 5) < LIM)
          nxt[flat] = cur[flat] + 2.f*cur[flat + sp32] + cur[flat + 2*sp32];
      }
      __syncthreads();
      storeT(nxt, l);
      cur = nxt; nxt = (l & 1) ? Bb : Ab;
    }
  }
  __syncthreads();
  {
    for (int e2 = 0; e2 < 16; e2++){
      int flat = e2*256 + tid;
      if ((flat >> 5) < 127){
        Ab[flat] = Xb[flat] + Xb[flat + 32];
        Db[flat] = Xb[flat + 32];
      }
    }
    __syncthreads();
    storeArr(Ab, 10); storeArr(Db, 19);
    float* bc = Ab; float* mc = Db; float* bn = Xb; float* mn = Bb;
    #pragma unroll
    for (int l = 2; l <= 5; l++){
      int sp = 1 << (l-1), sp32 = sp*32;
      int LIM = 129 - (1 << l);
      float fs = (float)sp;
      for (int e2 = 0; e2 < 16; e2++){
        int flat = e2*256 + tid;
        if ((flat >> 5) < LIM){
          float bwv = bc[flat + sp32];
          bn[flat] = bc[flat] + bwv;
          mn[flat] = mc[flat] + mc[flat + sp32] + fs*bwv;
        }
      }
      __syncthreads();
      storeArr(bn, 9 + l); storeArr(mn, 18 + l);
      float* t1 = bc; bc = bn; bn = t1;
      float* t2 = mc; mc = mn; mn = t2;
    }
  }
}

__device__ void gen2Body(const float* __restrict__ S1p, const float* __restrict__ S2p,
                         const float* __restrict__ R1p, __hip_bfloat16* __restrict__ tr,
                         int gb0, int nG, int tid, int s0, long tR){
  int gb = (gb0 & 7) * (nG >> 3) + (gb0 >> 3);
  int bl = gb / G2T, bx = gb - bl*G2T;
  int i = tid & 31, ug = tid >> 5;
  ushort* trb = (ushort*)tr + (size_t)(s0 + bl) * tR * 32;
  const float* s1 = S1p + (size_t)bl * SROWS * 32 + i;
  const float* s2 = S2p + (size_t)bl * SROWS * 32 + i;
  const float* r1 = R1p + (size_t)bl * SROWS * 32 + i;
  for (int e = 0; e < 2; e++){
    int u = -SNLO + bx*16 + e*8 + ug;
    size_t ns = (size_t)(u + SNLO) * 32;
    float s1_0 = s1[ns], s1_1 = s1[ns + 32];
    float s2_0 = s2[ns], s2_1 = s2[ns + 32];
    float r1_0 = r1[ns];
    {
      unsigned p = (unsigned)(u + PAD);
      if (p < (unsigned)(SEQ + 2*PAD))
        trb[((size_t)(arrOff(0) + p))*32 + i] = bfb(s1_1 - s1_0);
    }
    #pragma unroll
    for (int li = 0; li < 4; li++){
      const int l = 6 + li;
      const int s = 1 << l;
      float sa = s2[ns + (size_t)s*32],      sb = s2[ns + (size_t)(s+1)*32];
      float sc2 = s2[ns + (size_t)(2*s)*32], sd = s2[ns + (size_t)(2*s+1)*32];
      float Tv = (sc2 + sd) - 2.f*(sa + sb) + (s2_0 + s2_1);
      float b1v = s1[ns + (size_t)s*32] - s1_0;
      float mv  = (r1[ns + (size_t)s*32] - r1_0) - (float)u * b1v;
      {
        int ulo = -(2*s - 1);
        unsigned p = (unsigned)(u - (ulo - PAD));
        if (p < (unsigned)(SEQ - ulo + 2*PAD))
          trb[((size_t)(arrOff(l) + p))*32 + i] = bfb(Tv);
      }
      {
        int ulo = -(s - 1);
        unsigned p = (unsigned)(u - (ulo - PAD));
        unsigned rows = (unsigned)(SEQ - ulo + 2*PAD);
        if (p < rows){
          trb[((size_t)(arrOff(9 + l) + p))*32 + i]  = bfb(b1v);
          trb[((size_t)(arrOff(18 + l) + p))*32 + i] = bfb(mv);
        }
      }
    }
  }
}

// ================= fused kernels =================

__global__ __launch_bounds__(256) void fuseA_k(const float* __restrict__ x,
                                               const float* __restrict__ kern,
                                               const float* __restrict__ cen,
                                               float* __restrict__ invn,
                                               int4* __restrict__ stab,
                                               double* __restrict__ tmp,
                                               double* __restrict__ tmpT,
                                               __hip_bfloat16* __restrict__ tr,
                                               int nP1, int nNorm, int nPfs, int b0, long tR){
  __shared__ __align__(16) char shm[65536];
  int bid = blockIdx.x, tid = threadIdx.x;
  if (bid < nP1){ p1Body(x, tr, bid, tid, shm, b0, tR); return; }
  bid -= nP1;
  if (bid < nNorm){ normBody(kern, cen, invn, bid, tid, shm); return; }
  bid -= nNorm;
  if (nNorm > 0 && bid < 2){ setupBody(stab, bid, tid); return; }
  if (nNorm > 0) bid -= 2;
  if (bid < nPfs) pfsBody(x, tmp, tmpT, bid, tid, shm);
}

__global__ __launch_bounds__(256) void fuseB_k(const float* __restrict__ kern,
                                               const float* __restrict__ cen,
                                               const float* __restrict__ invn,
                                               __hip_bfloat16* __restrict__ wts,
                                               const float* __restrict__ x,
                                               const double* __restrict__ tmp,
                                               const double* __restrict__ tmpT,
                                               float* __restrict__ S1c, float* __restrict__ S2c,
                                               float* __restrict__ R1c,
                                               int nWts, int nPfe, int b0){
  int bid = blockIdx.x, tid = threadIdx.x;
  if (bid < nWts){ wtsBody(kern, cen, invn, wts, bid, tid); return; }
  bid -= nWts;
  if (bid < nPfe) pfeBody(x, tmp, tmpT, S1c, S2c, R1c, bid, tid, b0);
}

__global__ __launch_bounds__(256) void fuseC_k(const float* __restrict__ S1a,
                                               const float* __restrict__ S2a,
                                               const float* __restrict__ R1a,
                                               __hip_bfloat16* __restrict__ tr,
                                               int nGen2, int s0g, long tR,
                                               const float* __restrict__ x,
                                               const double* __restrict__ tmp,
                                               const double* __restrict__ tmpT,
                                               float* __restrict__ S1b, float* __restrict__ S2b,
                                               float* __restrict__ R1b,
                                               int nPfe, int b0p){
  int bid = blockIdx.x, tid = threadIdx.x;
  if (bid < nGen2){ gen2Body(S1a, S2a, R1a, tr, bid, nGen2, tid, s0g, tR); return; }
  bid -= nGen2;
  if (bid < nPfe) pfeBody(x, tmp, tmpT, S1b, S2b, R1b, bid, tid, b0p);
}

// ================= GEMM (r13/r16-proven best: 2-deep pipeline) =================
__device__ inline void gload16(const void* g, void* l){
  __builtin_amdgcn_global_load_lds(
      (const __attribute__((address_space(1))) void*)g,
      (__attribute__((address_space(3))) void*)l, 16, 0, 0);
}

__global__ __launch_bounds__(256) void gemm8_k(const short* __restrict__ tr,
                                               const short* __restrict__ wts,
                                               const int4* __restrict__ stab,
                                               float* __restrict__ out,
                                               int b0, long tR){
  __shared__ int4 sstab[NSTEP];
  __shared__ __align__(16) char smem[33792];
  short* Wlds = (short*)smem;
  int tid = threadIdx.x, wid = tid >> 6, lane = tid & 63;
  int N = gridDim.x;
  int wg = (blockIdx.x & 7) * (N >> 3) + (blockIdx.x >> 3);
  int bl = wg >> 6, T0 = (wg & 63) << 8;
  int b = b0 + bl;
  int rowlane = lane & 15, chunk = lane >> 4;
  const short* trb = tr + (size_t)bl * tR * 32;
  const char* wbase = (const char*)wts;
  int rowbase = wid*64 + rowlane;
  int chunkoff = chunk*8;
  int voffA = rowbase*32 + chunkoff;
  int offw = (rowlane*32 + chunk*8) ^ (((rowlane >> 1) & 3) << 3);
  f32x4 acc00={0,0,0,0}, acc01={0,0,0,0}, acc10={0,0,0,0}, acc11={0,0,0,0};
  f32x4 acc20={0,0,0,0}, acc21={0,0,0,0}, acc30={0,0,0,0}, acc31={0,0,0,0};

  for (int k = tid; k < NSTEP; k += 256) sstab[k] = stab[k];

  auto stageW = [&](int g, int buf){
    const char* src = wbase + (size_t)g*16384 + wid*1024 + lane*16;
    char* dst = smem + buf*16384 + wid*1024;
    #pragma unroll
    for (int k = 0; k < 4; k++)
      gload16(src + k*4096, dst + k*4096);
  };

  short8 a0A,a1A,a2A,a3A, a0B,a1B,a2B,a3B;
  int acA = 0, acB = 0;

#define PREFA(s, A0_,A1_,A2_,A3_, AC) { \
    int sc_ = (s) < NSTEP ? (s) : NSTEP-1; \
    int4 EE = sstab[sc_]; \
    int ey_ = __builtin_amdgcn_readfirstlane(EE.y); \
    int ez_ = __builtin_amdgcn_readfirstlane(EE.z); \
    int ew_ = __builtin_amdgcn_readfirstlane(EE.w); \
    AC = ((s) < NSTEP) && (T0 >= ey_) && (T0 <= ez_); \
    int base_ = T0 - ey_ - 127; \
    int rowsM1_ = ez_ - ey_ + 1; \
    const short* gb = trb + (size_t)ew_ * 32; \
    if (base_ >= 0 && base_ + 255 <= rowsM1_){ \
      const short* p_ = gb + (size_t)base_*32 + voffA; \
      A0_ = *(const short8*)(p_); \
      A1_ = *(const short8*)(p_ + 512); \
      A2_ = *(const short8*)(p_ + 1024); \
      A3_ = *(const short8*)(p_ + 1536); \
    } else { \
      int rel = base_ + rowbase; \
      int r0_ = rel;      r0_ = r0_ < 0 ? 0 : (r0_ > rowsM1_ ? rowsM1_ : r0_); \
      int r1_ = rel + 16; r1_ = r1_ < 0 ? 0 : (r1_ > rowsM1_ ? rowsM1_ : r1_); \
      int r2_ = rel + 32; r2_ = r2_ < 0 ? 0 : (r2_ > rowsM1_ ? rowsM1_ : r2_); \
      int r3_ = rel + 48; r3_ = r3_ < 0 ? 0 : (r3_ > rowsM1_ ? rowsM1_ : r3_); \
      A0_ = *(const short8*)(gb + r0_*32 + chunkoff); \
      A1_ = *(const short8*)(gb + r1_*32 + chunkoff); \
      A2_ = *(const short8*)(gb + r2_*32 + chunkoff); \
      A3_ = *(const short8*)(gb + r3_*32 + chunkoff); } }

#define CONS(kk, cb, A0_,A1_,A2_,A3_, AC) if (AC){ \
    const short* wp = Wlds + (cb)*8192 + (kk)*1024 + offw; \
    short8 w0_ = *(const short8*)wp; \
    short8 w1_ = *(const short8*)(wp + 512); \
    acc00 = __builtin_amdgcn_mfma_f32_16x16x32_bf16(A0_, w0_, acc00, 0,0,0); \
    acc01 = __builtin_amdgcn_mfma_f32_16x16x32_bf16(A0_, w1_, acc01, 0,0,0); \
    acc10 = __builtin_amdgcn_mfma_f32_16x16x32_bf16(A1_, w0_, acc10, 0,0,0); \
    acc11 = __builtin_amdgcn_mfma_f32_16x16x32_bf16(A1_, w1_, acc11, 0,0,0); \
    acc20 = __builtin_amdgcn_mfma_f32_16x16x32_bf16(A2_, w0_, acc20, 0,0,0); \
    acc21 = __builtin_amdgcn_mfma_f32_16x16x32_bf16(A2_, w1_, acc21, 0,0,0); \
    acc30 = __builtin_amdgcn_mfma_f32_16x16x32_bf16(A3_, w0_, acc30, 0,0,0); \
    acc31 = __builtin_amdgcn_mfma_f32_16x16x32_bf16(A3_, w1_, acc31, 0,0,0); }

  stageW(0, 0);
  asm volatile("s_waitcnt vmcnt(0)" ::: "memory");
  __syncthreads();

  PREFA(0, a0A,a1A,a2A,a3A, acA)
  PREFA(1, a0B,a1B,a2B,a3B, acB)
  int cbuf = 0;
  for (int g = 0; g < NGRP; ++g){
    if (g + 1 < NGRP) stageW(g + 1, cbuf ^ 1);
    int sb = g*GSTEPS;
    #pragma unroll
    for (int k = 0; k < GSTEPS; k += 2){
      CONS(k,   cbuf, a0A,a1A,a2A,a3A, acA)
      PREFA(sb+k+2, a0A,a1A,a2A,a3A, acA)
      CONS(k+1, cbuf, a0B,a1B,a2B,a3B, acB)
      PREFA(sb+k+3, a0B,a1B,a2B,a3B, acB)
    }
    asm volatile("s_waitcnt vmcnt(8)" ::: "memory");
    __builtin_amdgcn_s_barrier();
    cbuf ^= 1;
  }

  {
    float* Ob = (float*)smem;
    int r0e = wid*64 + chunk*4;
    for (int r = 0; r < 4; r++){
      Ob[(r0e +  0 + r)*33 + rowlane]      = acc00[r];
      Ob[(r0e +  0 + r)*33 + rowlane + 16] = acc01[r];
      Ob[(r0e + 16 + r)*33 + rowlane]      = acc10[r];
      Ob[(r0e + 16 + r)*33 + rowlane + 16] = acc11[r];
      Ob[(r0e + 32 + r)*33 + rowlane]      = acc20[r];
      Ob[(r0e + 32 + r)*33 + rowlane + 16] = acc21[r];
      Ob[(r0e + 48 + r)*33 + rowlane]      = acc30[r];
      Ob[(r0e + 48 + r)*33 + rowlane + 16] = acc31[r];
    }
    __syncthreads();
    for (int r = 0; r < 32; r++){
      int flat = r*256 + tid;
      int o = flat >> 8, t = flat & 255;
      out[((size_t)(b*32 + o) << 14) + T0 + t] = Ob[t*33 + o];
    }
  }
}

// ================= launcher =================
extern "C" void kernel_launch(void* const* d_in, const int* in_sizes, int n_in,
                              void* d_out, int out_size, void* d_ws, size_t ws_size,
                              hipStream_t stream) {
  const float* x    = (const float*)d_in[0];
  const float* kern = (const float*)d_in[1];
  const float* cen  = (const float*)d_in[2];
  float* out = (float*)d_out;
  char* ws = (char*)d_ws;

  long tR = totRows();
  size_t oWts  = 4096;
  size_t wtsBytes = (size_t)NGRP * 16384;
  size_t oStab = (oWts + wtsBytes + 255) & ~(size_t)255;
  size_t oTmp  = (oStab + (size_t)NSTEP*16 + 1023) & ~(size_t)1023;
  size_t tmpBytes  = (size_t)8*32*256*12*8;
  size_t tmpTBytes = (size_t)8*32*3*8;
  size_t oTr   = (oTmp + tmpBytes + tmpTBytes + 1023) & ~(size_t)1023;

  size_t trB_per = (size_t)tR * 64;
  size_t sB_per  = (size_t)SROWS * 128;

  float* invn = (float*)ws;
  __hip_bfloat16* wts = (__hip_bfloat16*)(ws + oWts);
  int4* stab = (int4*)(ws + oStab);
  double* tmp  = (double*)(ws + oTmp);
  double* tmpT = (double*)(ws + oTmp + tmpBytes);
  __hip_bfloat16* tr = (__hip_bfloat16*)(ws + oTr);

  int CH = 0, SC = 1, DUP = 1;
  {
    int scs[7] = {8,4,4,2,2,1,1};
    int dps[7] = {1,2,1,2,1,2,1};
    for (int ci = 0; ci < 7; ci++){
      size_t need = oTr + 8*trB_per + (size_t)3*dps[ci]*scs[ci]*sB_per;
      if (need <= ws_size){ CH = 8; SC = scs[ci]; DUP = dps[ci]; break; }
    }
    if (CH == 0){
      int cc[5] = {4,4,2,2,1};
      int ss[5] = {4,2,2,1,1};
      for (int ci = 0; ci < 5; ci++){
        size_t need = oTr + (size_t)cc[ci]*trB_per + (size_t)3*ss[ci]*sB_per;
        if (need <= ws_size){ CH = cc[ci]; SC = ss[ci]; DUP = 1; break; }
      }
      if (CH == 0){ CH = 1; SC = 1; DUP = 1; }
    }
  }
  size_t oS = oTr + (size_t)CH * trB_per;
  auto S1p = [&](int p){ return (float*)(ws + oS + ((size_t)(0*DUP + p))*SC*sB_per); };
  auto S2p = [&](int p){ return (float*)(ws + oS + ((size_t)(1*DUP + p))*SC*sB_per); };
  auto R1p = [&](int p){ return (float*)(ws + oS + ((size_t)(2*DUP + p))*SC*sB_per); };

  if (CH == 8){
    int nch = 8 / SC;
    fuseA_k<<<8*P1T + 1024 + 2 + 256, 256, 0, stream>>>(x, kern, cen, invn, stab, tmp, tmpT, tr,
                                                        8*P1T, 1024, 256, 0, tR);
    fuseB_k<<<NSTEP + SC*128, 256, 0, stream>>>(kern, cen, invn, wts, x, tmp, tmpT,
                                                S1p(0), S2p(0), R1p(0), NSTEP, SC*128, 0);
    for (int k = 0; k < nch; k++){
      int pa = (DUP == 2) ? (k & 1) : 0;
      int pb = (DUP == 2) ? ((k + 1) & 1) : 0;
      bool nxt = (k + 1 < nch);
      if (DUP == 2 && nxt){
        fuseC_k<<<SC*G2T + SC*128, 256, 0, stream>>>(S1p(pa), S2p(pa), R1p(pa), tr, SC*G2T, k*SC, tR,
                                                     x, tmp, tmpT, S1p(pb), S2p(pb), R1p(pb),
                                                     SC*128, (k+1)*SC);
      } else {
        fuseC_k<<<SC*G2T, 256, 0, stream>>>(S1p(pa), S2p(pa), R1p(pa), tr, SC*G2T, k*SC, tR,
                                            x, tmp, tmpT, S1p(0), S2p(0), R1p(0), 0, 0);
        if (nxt)
          fuseB_k<<<SC*128, 256, 0, stream>>>(kern, cen, invn, wts, x, tmp, tmpT,
                                              S1p(0), S2p(0), R1p(0), 0, SC*128, (k+1)*SC);
      }
    }
    gemm8_k<<<8*64, 256, 0, stream>>>((const short*)tr, (const short*)wts, stab, out, 0, tR);
  } else {
    for (int b0 = 0; b0 < 8; b0 += CH){
      fuseA_k<<<CH*P1T + (b0 == 0 ? 1024 + 2 + 256 : 0), 256, 0, stream>>>(
          x, kern, cen, invn, stab, tmp, tmpT, tr,
          CH*P1T, b0 == 0 ? 1024 : 0, b0 == 0 ? 256 : 0, b0, tR);
      for (int s0 = 0; s0 < CH; s0 += SC){
        fuseB_k<<<(b0 == 0 && s0 == 0 ? NSTEP : 0) + SC*128, 256, 0, stream>>>(
            kern, cen, invn, wts, x, tmp, tmpT, S1p(0), S2p(0), R1p(0),
            (b0 == 0 && s0 == 0) ? NSTEP : 0, SC*128, b0 + s0);
        fuseC_k<<<SC*G2T, 256, 0, stream>>>(S1p(0), S2p(0), R1p(0), tr, SC*G2T, s0, tR,
                                            x, tmp, tmpT, S1p(0), S2p(0), R1p(0), 0, 0);
      }
      gemm8_k<<<CH*64, 256, 0, stream>>>((const short*)tr, (const short*)wts, stab, out, b0, tR);
    }
  }
}